// Round 2
// baseline (320.430 us; speedup 1.0000x reference)
//
#include <hip/hip_runtime.h>
#include <math.h>

// ---------------------------------------------------------------------------
// ActorNetwork fused kernel, round 2: LDS-staged hot-loop weights.
//
// Exact algebraic folds (unchanged from round 1):
//   * W_cq / W_ck are dead (softmax over seq_len=1 == 1).
//   * score = intru . (own_e @ (W_q^T W_k))      [precomputed wQK]
//   * v_att = (sum_n alpha_n intru_n) @ W_v.T    [pool-then-project]
//   * mo    = concat @ W_fold^T + b_mo,  W_fold = blockdiag-fold of W_mo,W_cv
//
// Round-2 changes (theory: latency-bound, VALUBusy 20%, all pipes idle):
//   1. W_s1 / W_s2^T / b_s1 / b_s2 staged in LDS per block. Hot-loop reads
//      are wave-uniform ds_read_b128 broadcasts (conflict-free, deeply
//      pipelined) instead of SGPR-pressure-serialized s_loads from global.
//   2. concatL rows are wave-private (8 lanes/elem x 8 elems = 1 wave), so
//      all barriers except the weight-staging one are removed; waves run
//      fully decoupled. moL eliminated (qk via v_att slot, mo via own/env
//      slots of concatL).
//   3. qk re-read from LDS in each outer iteration's epilogue to keep the
//      k-loop register set at P[64]+acc[64]+sj[16] (~170 VGPR, no spill).
// ---------------------------------------------------------------------------

#define WS_S2T   0        // [64][64]  W_s2^T
#define WS_OWNT  4096     // [16][64]  W_own^T
#define WS_QK    5120     // [64][64]  W_q^T @ W_k
#define WS_FOLDT 9216     // [192][128] W_fold^T
#define WS_A1T   33792    // [128][64] W_a1^T
#define WS_ENVT  41984    // [64][64]  W_env^T
#define WS_TOTAL 46080

__global__ void actor_setup(
    const float* __restrict__ wOwn, const float* __restrict__ wEnv,
    const float* __restrict__ wS2,  const float* __restrict__ wQ,
    const float* __restrict__ wK,   const float* __restrict__ wCv,
    const float* __restrict__ wMo,  const float* __restrict__ wA1,
    float* __restrict__ ws)
{
    int t = blockIdx.x * 256 + threadIdx.x;
    if (t < 4096) {                        // wS2T[k][d] = W_s2[d][k]
        int k = t >> 6, d = t & 63;
        ws[WS_S2T + t] = wS2[d * 64 + k];
    } else if (t < 5120) {                 // wOwnT[k][d] = W_own[d][k]
        int u = t - 4096; int k = u >> 6, d = u & 63;
        ws[t] = wOwn[d * 16 + k];
    } else if (t < 9216) {                 // wQK[e][dp] = sum_d W_q[d][e]*W_k[d][dp]
        int u = t - 5120; int e = u >> 6, dp = u & 63;
        float acc = 0.f;
        for (int d = 0; d < 64; ++d) acc += wQ[d * 64 + e] * wK[d * 64 + dp];
        ws[t] = acc;
    } else if (t < 33792) {                // wFoldT[i][j], i = h*64+dp
        int u = t - 9216; int i = u >> 7, j = u & 127;
        int h = i >> 6, dp = i & 63;
        float acc = 0.f;
        for (int d = 0; d < 64; ++d)
            acc += wMo[j * 192 + h * 64 + d] * wCv[d * 64 + dp];
        ws[t] = acc;
    } else if (t < 41984) {                // wA1T[j][o] = W_a1[o][j]
        int u = t - 33792; int j = u >> 6, o = u & 63;
        ws[t] = wA1[o * 128 + j];
    } else if (t < WS_TOTAL) {             // wEnvT[k][d] = W_env[d][k]
        int u = t - 41984; int k = u >> 6, d = u & 63;
        ws[t] = wEnv[d * 64 + k];
    }
}

#define ELPB 32   // batch elements per 256-thread block (8 lanes each)

__global__ __launch_bounds__(256, 2) void actor_main(
    const float* __restrict__ s0g, const float* __restrict__ s1g,
    const float* __restrict__ s2g,
    const float* __restrict__ bOwn, const float* __restrict__ bEnv,
    const float* __restrict__ wS1g, const float* __restrict__ bS1g,
    const float* __restrict__ bS2g, const float* __restrict__ wV,
    const float* __restrict__ bMo,  const float* __restrict__ bA1,
    const float* __restrict__ wA2,  const float* __restrict__ bA2,
    const float* __restrict__ ws,   float* __restrict__ outg)
{
    const float* __restrict__ wOwnT  = ws + WS_OWNT;
    const float* __restrict__ wQK    = ws + WS_QK;
    const float* __restrict__ wFoldT = ws + WS_FOLDT;
    const float* __restrict__ wA1T   = ws + WS_A1T;
    const float* __restrict__ wEnvT  = ws + WS_ENVT;

    // [own 0:64 | env 64:128 | qk-then-vatt 128:192]; 196 stride: el*196 % 32
    // = el*4 -> consecutive els hit disjoint bank quads on b128 reads.
    __shared__ float concatL[ELPB][196];
    __shared__ float wS1L[64 * 16];
    __shared__ float wS2L[64 * 64];
    __shared__ float bS1L[64];
    __shared__ float bS2L[64];

    const int tid = threadIdx.x;
    const int el  = tid >> 3;        // element within block
    const int g   = tid & 7;         // lane within 8-lane group
    const int b   = blockIdx.x * ELPB + el;

    // ---------------- stage hot-loop weights into LDS (coalesced, once)
    {
        const float4* s2t4 = reinterpret_cast<const float4*>(ws + WS_S2T);
        float4*       d2   = reinterpret_cast<float4*>(wS2L);
        #pragma unroll
        for (int q = 0; q < 4; ++q) d2[tid + 256 * q] = s2t4[tid + 256 * q];
        reinterpret_cast<float4*>(wS1L)[tid] =
            reinterpret_cast<const float4*>(wS1g)[tid];
        if (tid < 16)
            reinterpret_cast<float4*>(bS1L)[tid] =
                reinterpret_cast<const float4*>(bS1g)[tid];
        else if (tid < 32)
            reinterpret_cast<float4*>(bS2L)[tid - 16] =
                reinterpret_cast<const float4*>(bS2g)[tid - 16];
    }

    // ---------------- own_e slice (8 dims/lane) -> concatL[0..63]
    float s0r[16];
    {
        const float4* p = reinterpret_cast<const float4*>(s0g + (size_t)b * 16);
        #pragma unroll
        for (int q = 0; q < 4; ++q) {
            float4 v = p[q];
            s0r[q*4+0]=v.x; s0r[q*4+1]=v.y; s0r[q*4+2]=v.z; s0r[q*4+3]=v.w;
        }
    }
    {
        float4 b0 = *reinterpret_cast<const float4*>(bOwn + g*8);
        float4 b1 = *reinterpret_cast<const float4*>(bOwn + g*8 + 4);
        float ow[8] = {b0.x,b0.y,b0.z,b0.w,b1.x,b1.y,b1.z,b1.w};
        #pragma unroll
        for (int k = 0; k < 16; ++k) {
            float sk = s0r[k];
            const float* wr = wOwnT + k*64 + g*8;
            float4 w0 = *reinterpret_cast<const float4*>(wr);
            float4 w1 = *reinterpret_cast<const float4*>(wr + 4);
            ow[0]=fmaf(sk,w0.x,ow[0]); ow[1]=fmaf(sk,w0.y,ow[1]);
            ow[2]=fmaf(sk,w0.z,ow[2]); ow[3]=fmaf(sk,w0.w,ow[3]);
            ow[4]=fmaf(sk,w1.x,ow[4]); ow[5]=fmaf(sk,w1.y,ow[5]);
            ow[6]=fmaf(sk,w1.z,ow[6]); ow[7]=fmaf(sk,w1.w,ow[7]);
        }
        #pragma unroll
        for (int j = 0; j < 8; ++j) ow[j] = fmaxf(ow[j], 0.f);
        *reinterpret_cast<float4*>(&concatL[el][g*8])     = make_float4(ow[0],ow[1],ow[2],ow[3]);
        *reinterpret_cast<float4*>(&concatL[el][g*8 + 4]) = make_float4(ow[4],ow[5],ow[6],ow[7]);
    }

    // ---------------- qk slice -> concatL[128..191]  (wave-local RAW on own)
    {
        float qs[8] = {0,0,0,0,0,0,0,0};
        #pragma unroll 2
        for (int e4 = 0; e4 < 16; ++e4) {
            float4 c4 = *reinterpret_cast<const float4*>(&concatL[el][e4*4]);
            #pragma unroll
            for (int q = 0; q < 4; ++q) {
                float oe = (q==0)?c4.x:(q==1)?c4.y:(q==2)?c4.z:c4.w;
                const float* wr = wQK + (e4*4+q)*64 + g*8;
                float4 w0 = *reinterpret_cast<const float4*>(wr);
                float4 w1 = *reinterpret_cast<const float4*>(wr + 4);
                qs[0]=fmaf(oe,w0.x,qs[0]); qs[1]=fmaf(oe,w0.y,qs[1]);
                qs[2]=fmaf(oe,w0.z,qs[2]); qs[3]=fmaf(oe,w0.w,qs[3]);
                qs[4]=fmaf(oe,w1.x,qs[4]); qs[5]=fmaf(oe,w1.y,qs[5]);
                qs[6]=fmaf(oe,w1.z,qs[6]); qs[7]=fmaf(oe,w1.w,qs[7]);
            }
        }
        *reinterpret_cast<float4*>(&concatL[el][128 + g*8])     = make_float4(qs[0],qs[1],qs[2],qs[3]);
        *reinterpret_cast<float4*>(&concatL[el][128 + g*8 + 4]) = make_float4(qs[4],qs[5],qs[6],qs[7]);
    }

    __syncthreads();   // the ONLY barrier: weight staging visible to all waves

    // ---------------- neighbor loop: 4 neighbors/lane, online softmax
    float P[64];
    #pragma unroll
    for (int d = 0; d < 64; ++d) P[d] = 0.f;
    float mrun = -1e30f, Srun = 0.f;

    const float* s2b = s2g + (size_t)b * 512;
    #pragma unroll 1
    for (int it = 0; it < 4; ++it) {
        const int n = it*8 + g;
        float sj[16];
        {
            const float4* p = reinterpret_cast<const float4*>(s2b + n*16);
            #pragma unroll
            for (int q = 0; q < 4; ++q) {
                float4 v = p[q];
                sj[q*4+0]=v.x; sj[q*4+1]=v.y; sj[q*4+2]=v.z; sj[q*4+3]=v.w;
            }
        }
        float acc[64];
        #pragma unroll
        for (int d4 = 0; d4 < 16; ++d4) {
            float4 bv = *reinterpret_cast<const float4*>(bS2L + d4*4);   // broadcast
            acc[d4*4+0]=bv.x; acc[d4*4+1]=bv.y; acc[d4*4+2]=bv.z; acc[d4*4+3]=bv.w;
        }
        #pragma unroll 2
        for (int k = 0; k < 64; ++k) {
            const float4* w1p = reinterpret_cast<const float4*>(wS1L + k*16);  // broadcast
            float4 wa = w1p[0], wb = w1p[1], wc = w1p[2], wd = w1p[3];
            float hk = bS1L[k];
            hk = fmaf(sj[0],  wa.x, hk); hk = fmaf(sj[1],  wa.y, hk);
            hk = fmaf(sj[2],  wa.z, hk); hk = fmaf(sj[3],  wa.w, hk);
            hk = fmaf(sj[4],  wb.x, hk); hk = fmaf(sj[5],  wb.y, hk);
            hk = fmaf(sj[6],  wb.z, hk); hk = fmaf(sj[7],  wb.w, hk);
            hk = fmaf(sj[8],  wc.x, hk); hk = fmaf(sj[9],  wc.y, hk);
            hk = fmaf(sj[10], wc.z, hk); hk = fmaf(sj[11], wc.w, hk);
            hk = fmaf(sj[12], wd.x, hk); hk = fmaf(sj[13], wd.y, hk);
            hk = fmaf(sj[14], wd.z, hk); hk = fmaf(sj[15], wd.w, hk);
            hk = fmaxf(hk, 0.f);
            const float4* w2p = reinterpret_cast<const float4*>(wS2L + k*64);  // broadcast
            #pragma unroll
            for (int q = 0; q < 16; ++q) {
                float4 w = w2p[q];
                acc[q*4+0] = fmaf(hk, w.x, acc[q*4+0]);
                acc[q*4+1] = fmaf(hk, w.y, acc[q*4+1]);
                acc[q*4+2] = fmaf(hk, w.z, acc[q*4+2]);
                acc[q*4+3] = fmaf(hk, w.w, acc[q*4+3]);
            }
        }
        // relu + row-sum (mask) + score = intru . qk   (qk re-read from LDS)
        float rs0=0,rs1=0,rs2=0,rs3=0, t0=0,t1=0,t2=0,t3=0;
        #pragma unroll
        for (int d = 0; d < 64; d += 4) {
            float4 qv = *reinterpret_cast<const float4*>(&concatL[el][128 + d]);
            float a0=fmaxf(acc[d],0.f),  a1=fmaxf(acc[d+1],0.f);
            float a2=fmaxf(acc[d+2],0.f),a3=fmaxf(acc[d+3],0.f);
            acc[d]=a0; acc[d+1]=a1; acc[d+2]=a2; acc[d+3]=a3;
            rs0+=a0; rs1+=a1; rs2+=a2; rs3+=a3;
            t0=fmaf(a0,qv.x,t0); t1=fmaf(a1,qv.y,t1);
            t2=fmaf(a2,qv.z,t2); t3=fmaf(a3,qv.w,t3);
        }
        float rs = (rs0+rs1)+(rs2+rs3);
        float sc = ((t0+t1)+(t2+t3)) * 0.125f;      // / sqrt(64)
        bool valid = (rs != 0.f);                   // mask: mean(relu)!=0 <=> sum!=0
        float scv = valid ? sc : -1e30f;
        float nm = fmaxf(mrun, scv);
        float ascale = __expf(mrun - nm);
        float w = valid ? __expf(sc - nm) : 0.f;
        Srun = fmaf(Srun, ascale, w);
        #pragma unroll
        for (int d = 0; d < 64; ++d) P[d] = fmaf(P[d], ascale, w*acc[d]);
        mrun = nm;
    }

    // ---------------- combine flash states across the 8-lane group
    #pragma unroll
    for (int msk = 1; msk <= 4; msk <<= 1) {
        float mo_ = __shfl_xor(mrun, msk, 64);
        float So_ = __shfl_xor(Srun, msk, 64);
        float nm  = fmaxf(mrun, mo_);
        float aa  = __expf(mrun - nm);
        float bb  = __expf(mo_  - nm);
        Srun = fmaf(Srun, aa, So_*bb);
        #pragma unroll
        for (int d = 0; d < 64; ++d) {
            float Po = __shfl_xor(P[d], msk, 64);
            P[d] = fmaf(P[d], aa, Po*bb);
        }
        mrun = nm;
    }
    {
        float inv = (Srun > 0.f) ? (1.f / Srun) : 0.f;   // all-masked -> v_att = 0
        #pragma unroll
        for (int d = 0; d < 64; ++d) P[d] *= inv;        // pooled (pre-W_v)
    }

    // ---------------- v_att slice -> concatL[128..191] (overwrites qk; same wave)
    {
        float va[8];
        #pragma unroll
        for (int jj = 0; jj < 8; ++jj) {
            const float* wr = wV + (g*8 + jj)*64;
            float a0=0,a1=0,a2=0,a3=0;
            #pragma unroll
            for (int dp = 0; dp < 64; dp += 4) {
                float4 w4 = *reinterpret_cast<const float4*>(wr + dp);
                a0 = fmaf(P[dp+0], w4.x, a0);
                a1 = fmaf(P[dp+1], w4.y, a1);
                a2 = fmaf(P[dp+2], w4.z, a2);
                a3 = fmaf(P[dp+3], w4.w, a3);
            }
            va[jj] = (a0+a1)+(a2+a3);
        }
        *reinterpret_cast<float4*>(&concatL[el][128 + g*8])     = make_float4(va[0],va[1],va[2],va[3]);
        *reinterpret_cast<float4*>(&concatL[el][128 + g*8 + 4]) = make_float4(va[4],va[5],va[6],va[7]);
    }

    // ---------------- env slice -> concatL[64..127]
    {
        float4 b0 = *reinterpret_cast<const float4*>(bEnv + g*8);
        float4 b1 = *reinterpret_cast<const float4*>(bEnv + g*8 + 4);
        float ev[8] = {b0.x,b0.y,b0.z,b0.w,b1.x,b1.y,b1.z,b1.w};
        const float* s1b = s1g + (size_t)b * 64;
        #pragma unroll 2
        for (int k4 = 0; k4 < 16; ++k4) {
            float4 sv = *reinterpret_cast<const float4*>(s1b + k4*4);
            #pragma unroll
            for (int q = 0; q < 4; ++q) {
                float sk = (q==0)?sv.x:(q==1)?sv.y:(q==2)?sv.z:sv.w;
                const float* wr = wEnvT + (k4*4+q)*64 + g*8;
                float4 w0 = *reinterpret_cast<const float4*>(wr);
                float4 w1 = *reinterpret_cast<const float4*>(wr + 4);
                ev[0]=fmaf(sk,w0.x,ev[0]); ev[1]=fmaf(sk,w0.y,ev[1]);
                ev[2]=fmaf(sk,w0.z,ev[2]); ev[3]=fmaf(sk,w0.w,ev[3]);
                ev[4]=fmaf(sk,w1.x,ev[4]); ev[5]=fmaf(sk,w1.y,ev[5]);
                ev[6]=fmaf(sk,w1.z,ev[6]); ev[7]=fmaf(sk,w1.w,ev[7]);
            }
        }
        #pragma unroll
        for (int j = 0; j < 8; ++j) ev[j] = fmaxf(ev[j], 0.f);
        *reinterpret_cast<float4*>(&concatL[el][64 + g*8])     = make_float4(ev[0],ev[1],ev[2],ev[3]);
        *reinterpret_cast<float4*>(&concatL[el][64 + g*8 + 4]) = make_float4(ev[4],ev[5],ev[6],ev[7]);
    }

    // ---------------- mo = concat @ W_fold^T + b_mo  (16 outs/lane, wave-local)
    float mo[16];
    {
        const float* bm = bMo + g*16;
        #pragma unroll
        for (int q = 0; q < 4; ++q) {
            float4 v = *reinterpret_cast<const float4*>(bm + q*4);
            mo[q*4+0]=v.x; mo[q*4+1]=v.y; mo[q*4+2]=v.z; mo[q*4+3]=v.w;
        }
    }
    #pragma unroll 2
    for (int i4 = 0; i4 < 48; ++i4) {
        float4 c4 = *reinterpret_cast<const float4*>(&concatL[el][i4*4]);
        #pragma unroll
        for (int q = 0; q < 4; ++q) {
            float ci = (q==0)?c4.x:(q==1)?c4.y:(q==2)?c4.z:c4.w;
            const float* wr = wFoldT + (i4*4+q)*128 + g*16;
            #pragma unroll
            for (int u = 0; u < 4; ++u) {
                float4 w4 = *reinterpret_cast<const float4*>(wr + u*4);
                mo[u*4+0]=fmaf(ci,w4.x,mo[u*4+0]);
                mo[u*4+1]=fmaf(ci,w4.y,mo[u*4+1]);
                mo[u*4+2]=fmaf(ci,w4.z,mo[u*4+2]);
                mo[u*4+3]=fmaf(ci,w4.w,mo[u*4+3]);
            }
        }
    }
    // broadcast mo through concatL[el][0..127] (reads above all feed mo -> safe)
    #pragma unroll
    for (int q = 0; q < 4; ++q)
        *reinterpret_cast<float4*>(&concatL[el][g*16 + q*4]) =
            make_float4(mo[q*4],mo[q*4+1],mo[q*4+2],mo[q*4+3]);

    // ---------------- a = relu(mo @ W_a1^T + b_a1)  (8 outs/lane)
    float av[8];
    {
        float4 b0 = *reinterpret_cast<const float4*>(bA1 + g*8);
        float4 b1 = *reinterpret_cast<const float4*>(bA1 + g*8 + 4);
        av[0]=b0.x; av[1]=b0.y; av[2]=b0.z; av[3]=b0.w;
        av[4]=b1.x; av[5]=b1.y; av[6]=b1.z; av[7]=b1.w;
    }
    #pragma unroll 2
    for (int j4 = 0; j4 < 32; ++j4) {
        float4 m4 = *reinterpret_cast<const float4*>(&concatL[el][j4*4]);
        #pragma unroll
        for (int q = 0; q < 4; ++q) {
            float mj = (q==0)?m4.x:(q==1)?m4.y:(q==2)?m4.z:m4.w;
            const float* wr = wA1T + (j4*4+q)*64 + g*8;
            float4 w0 = *reinterpret_cast<const float4*>(wr);
            float4 w1 = *reinterpret_cast<const float4*>(wr + 4);
            av[0]=fmaf(mj,w0.x,av[0]); av[1]=fmaf(mj,w0.y,av[1]);
            av[2]=fmaf(mj,w0.z,av[2]); av[3]=fmaf(mj,w0.w,av[3]);
            av[4]=fmaf(mj,w1.x,av[4]); av[5]=fmaf(mj,w1.y,av[5]);
            av[6]=fmaf(mj,w1.z,av[6]); av[7]=fmaf(mj,w1.w,av[7]);
        }
    }
    #pragma unroll
    for (int j = 0; j < 8; ++j) av[j] = fmaxf(av[j], 0.f);

    // ---------------- out = tanh(a @ W_a2^T + b_a2)
    {
        float4 w0a = *reinterpret_cast<const float4*>(wA2 + g*8);
        float4 w0b = *reinterpret_cast<const float4*>(wA2 + g*8 + 4);
        float4 w1a = *reinterpret_cast<const float4*>(wA2 + 64 + g*8);
        float4 w1b = *reinterpret_cast<const float4*>(wA2 + 64 + g*8 + 4);
        float p0 = av[0]*w0a.x + av[1]*w0a.y + av[2]*w0a.z + av[3]*w0a.w
                 + av[4]*w0b.x + av[5]*w0b.y + av[6]*w0b.z + av[7]*w0b.w;
        float p1 = av[0]*w1a.x + av[1]*w1a.y + av[2]*w1a.z + av[3]*w1a.w
                 + av[4]*w1b.x + av[5]*w1b.y + av[6]*w1b.z + av[7]*w1b.w;
        #pragma unroll
        for (int msk = 1; msk <= 4; msk <<= 1) {
            p0 += __shfl_xor(p0, msk, 64);
            p1 += __shfl_xor(p1, msk, 64);
        }
        if (g == 0) {
            float o0 = tanhf(p0 + bA2[0]);
            float o1 = tanhf(p1 + bA2[1]);
            *reinterpret_cast<float2*>(outg + (size_t)b * 2) = make_float2(o0, o1);
        }
    }
}

extern "C" void kernel_launch(void* const* d_in, const int* in_sizes, int n_in,
                              void* d_out, int out_size, void* d_ws, size_t ws_size,
                              hipStream_t stream) {
    const float* s0   = (const float*)d_in[0];
    const float* s1   = (const float*)d_in[1];
    const float* s2   = (const float*)d_in[2];
    const float* wOwn = (const float*)d_in[3];
    const float* bOwn = (const float*)d_in[4];
    const float* wEnv = (const float*)d_in[5];
    const float* bEnv = (const float*)d_in[6];
    const float* wS1  = (const float*)d_in[7];
    const float* bS1  = (const float*)d_in[8];
    const float* wS2  = (const float*)d_in[9];
    const float* bS2  = (const float*)d_in[10];
    const float* wQ   = (const float*)d_in[11];
    const float* wK   = (const float*)d_in[12];
    const float* wV   = (const float*)d_in[13];
    // d_in[14] (W_cq) and d_in[15] (W_ck) are dead code in the reference.
    const float* wCv  = (const float*)d_in[16];
    const float* wMo  = (const float*)d_in[17];
    const float* bMo  = (const float*)d_in[18];
    const float* wA1  = (const float*)d_in[19];
    const float* bA1  = (const float*)d_in[20];
    const float* wA2  = (const float*)d_in[21];
    const float* bA2  = (const float*)d_in[22];
    float* ws  = (float*)d_ws;
    float* out = (float*)d_out;

    hipLaunchKernelGGL(actor_setup, dim3(WS_TOTAL / 256), dim3(256), 0, stream,
                       wOwn, wEnv, wS2, wQ, wK, wCv, wMo, wA1, ws);
    hipLaunchKernelGGL(actor_main, dim3(16384 / ELPB), dim3(256), 0, stream,
                       s0, s1, s2, bOwn, bEnv, wS1, bS1, bS2, wV,
                       bMo, bA1, wA2, bA2, ws, out);
}

// Round 3
// 186.363 us; speedup vs baseline: 1.7194x; 1.7194x over previous
//
#include <hip/hip_runtime.h>
#include <math.h>

// ---------------------------------------------------------------------------
// ActorNetwork, round 3: bf16 MFMA for the neighbor-encoder GEMMs.
//
// Exact algebraic folds (unchanged): W_cq/W_ck dead; score via wQK = W_q^T W_k;
// pool-then-project for W_v; W_fold = blockdiag fold of W_mo,W_cv.
//
// Round-3 changes (theory: r1/r2 were scratch-spill-bound — VGPR_Count=128
// vs >=150 live floats; WRITE_SIZE 17-49MB vs 131KB output):
//   * K2 computes intru via mfma_f32_16x16x32_bf16, swapped operands:
//     D = W @ X^T so D-frag: col(lane&15)=sample, row((lane>>4)*4+i)=feature.
//     GEMM1: H^T = W_s1 @ S2^T (K=16 padded to 32, zeros in A kill garbage B).
//     GEMM2: INTRU^T = W_s2 @ H^T (K=64, 2 k-tiles), H via pad-72 LDS rows.
//   * No-max softmax: scores/8 are O(1e-2) -> w = exp(s/8) directly; pool and
//     denom xor-reduced once per element. ~55 live VGPRs in hot path, no spill.
//   * K1 precomputes qk[b][64]; K3 = tail MLP (fp32, wave-private LDS rows).
// ---------------------------------------------------------------------------

typedef __attribute__((ext_vector_type(8))) short short8;
typedef __attribute__((ext_vector_type(4))) float f32x4;

// ws layout (4-byte units)
#define WS_A1F   0                         // [4 ht][64 lane][4 u32]  bf16 A-frags W_s1 (K-padded)
#define WS_A2F   1024                      // [4 dt x 2 kt][64 lane][4 u32] bf16 A-frags W_s2
#define WS_QK    3072                      // [64][64] W_q^T @ W_k
#define WS_FOLDT 7168                      // [192][128] W_fold^T
#define WS_A1T   31744                     // [128][64] W_a1^T
#define WS_ENVT  39936                     // [64][64] W_env^T
#define WS_OWNT  44032                     // [16][64] W_own^T
#define WS_WEND  45056
#define WS_QKB   45056                     // [16384][64] qk per element
#define WS_P     (45056 + 16384*64)        // [16384][64] pooled pre-W_v

static __device__ inline unsigned short f2bf(float x) {
    union { float f; unsigned u; } c; c.f = x;
    unsigned r = c.u + 0x7fff + ((c.u >> 16) & 1);   // RNE
    return (unsigned short)(r >> 16);
}
static __device__ inline unsigned pk2(float a, float b) {
    return (unsigned)f2bf(a) | ((unsigned)f2bf(b) << 16);
}

// ---------------------------------------------------------------- K0: setup
__global__ void actor_setup(
    const float* __restrict__ wOwn, const float* __restrict__ wEnv,
    const float* __restrict__ wS1,  const float* __restrict__ wS2,
    const float* __restrict__ wQ,   const float* __restrict__ wK,
    const float* __restrict__ wCv,  const float* __restrict__ wMo,
    const float* __restrict__ wA1,  float* __restrict__ ws)
{
    int t = blockIdx.x * 256 + threadIdx.x;
    unsigned* wsu = reinterpret_cast<unsigned*>(ws);
    if (t < 1024) {                        // A1 frags: A[m][k]=W_s1[ht*16+m][k], k<16 else 0
        int ht = t >> 8, rem = t & 255, lane = rem >> 2, jj = rem & 3;
        int q = lane >> 4, m = lane & 15;
        int row = ht * 16 + m, k0 = q * 8 + jj * 2;
        float v0 = (k0 < 16) ? wS1[row * 16 + k0]     : 0.f;
        float v1 = (k0 < 16) ? wS1[row * 16 + k0 + 1] : 0.f;
        wsu[WS_A1F + t] = pk2(v0, v1);
    } else if (t < 3072) {                 // A2 frags: A[m][k]=W_s2[dt*16+m][kt*32+k]
        int u = t - 1024;
        int f = u >> 8, rem = u & 255, lane = rem >> 2, jj = rem & 3;
        int q = lane >> 4, m = lane & 15;
        int dt = f >> 1, kt = f & 1;
        int row = dt * 16 + m, k = kt * 32 + q * 8 + jj * 2;
        wsu[WS_A2F + u] = pk2(wS2[row * 64 + k], wS2[row * 64 + k + 1]);
    } else if (t < 7168) {                 // wQK[e][dp]
        int u = t - 3072; int e = u >> 6, dp = u & 63;
        float acc = 0.f;
        for (int d = 0; d < 64; ++d) acc += wQ[d * 64 + e] * wK[d * 64 + dp];
        ws[WS_QK + u] = acc;
    } else if (t < 31744) {                // wFoldT[i][j], i = h*64+dp
        int u = t - 7168; int i = u >> 7, j = u & 127;
        int h = i >> 6, dp = i & 63;
        float acc = 0.f;
        for (int d = 0; d < 64; ++d)
            acc += wMo[j * 192 + h * 64 + d] * wCv[d * 64 + dp];
        ws[WS_FOLDT + u] = acc;
    } else if (t < 39936) {                // wA1T[j][o]
        int u = t - 31744; int j = u >> 6, o = u & 63;
        ws[WS_A1T + u] = wA1[o * 128 + j];
    } else if (t < 44032) {                // wEnvT[k][d]
        int u = t - 39936; int k = u >> 6, d = u & 63;
        ws[WS_ENVT + u] = wEnv[d * 64 + k];
    } else if (t < WS_WEND) {              // wOwnT[k][d]
        int u = t - 44032; int k = u >> 6, d = u & 63;
        ws[WS_OWNT + u] = wOwn[d * 16 + k];
    }
}

// ---------------------------------------------------------------- K1: qk pre
__global__ __launch_bounds__(256) void actor_pre(
    const float* __restrict__ s0g, const float* __restrict__ bOwn,
    const float* __restrict__ ws,  float* __restrict__ qkb)
{
    const float* __restrict__ wOwnT = ws + WS_OWNT;
    const float* __restrict__ wQK   = ws + WS_QK;
    __shared__ float ownL[32][68];
    const int tid = threadIdx.x;
    const int el = tid >> 3, g = tid & 7;
    const int b = blockIdx.x * 32 + el;

    float s0r[16];
    {
        const float4* p = reinterpret_cast<const float4*>(s0g + (size_t)b * 16);
        #pragma unroll
        for (int qq = 0; qq < 4; ++qq) {
            float4 v = p[qq];
            s0r[qq*4+0]=v.x; s0r[qq*4+1]=v.y; s0r[qq*4+2]=v.z; s0r[qq*4+3]=v.w;
        }
    }
    {
        float4 b0 = *reinterpret_cast<const float4*>(bOwn + g*8);
        float4 b1 = *reinterpret_cast<const float4*>(bOwn + g*8 + 4);
        float ow[8] = {b0.x,b0.y,b0.z,b0.w,b1.x,b1.y,b1.z,b1.w};
        #pragma unroll
        for (int k = 0; k < 16; ++k) {
            float sk = s0r[k];
            const float* wr = wOwnT + k*64 + g*8;
            float4 w0 = *reinterpret_cast<const float4*>(wr);
            float4 w1 = *reinterpret_cast<const float4*>(wr + 4);
            ow[0]=fmaf(sk,w0.x,ow[0]); ow[1]=fmaf(sk,w0.y,ow[1]);
            ow[2]=fmaf(sk,w0.z,ow[2]); ow[3]=fmaf(sk,w0.w,ow[3]);
            ow[4]=fmaf(sk,w1.x,ow[4]); ow[5]=fmaf(sk,w1.y,ow[5]);
            ow[6]=fmaf(sk,w1.z,ow[6]); ow[7]=fmaf(sk,w1.w,ow[7]);
        }
        #pragma unroll
        for (int j = 0; j < 8; ++j) ow[j] = fmaxf(ow[j], 0.f);
        *reinterpret_cast<float4*>(&ownL[el][g*8])     = make_float4(ow[0],ow[1],ow[2],ow[3]);
        *reinterpret_cast<float4*>(&ownL[el][g*8 + 4]) = make_float4(ow[4],ow[5],ow[6],ow[7]);
    }
    // same-wave RAW on ownL (wave-private row) — no barrier
    {
        float qs[8] = {0,0,0,0,0,0,0,0};
        #pragma unroll 2
        for (int e4 = 0; e4 < 16; ++e4) {
            float4 c4 = *reinterpret_cast<const float4*>(&ownL[el][e4*4]);
            #pragma unroll
            for (int qq = 0; qq < 4; ++qq) {
                float oe = (qq==0)?c4.x:(qq==1)?c4.y:(qq==2)?c4.z:c4.w;
                const float* wr = wQK + (e4*4+qq)*64 + g*8;
                float4 w0 = *reinterpret_cast<const float4*>(wr);
                float4 w1 = *reinterpret_cast<const float4*>(wr + 4);
                qs[0]=fmaf(oe,w0.x,qs[0]); qs[1]=fmaf(oe,w0.y,qs[1]);
                qs[2]=fmaf(oe,w0.z,qs[2]); qs[3]=fmaf(oe,w0.w,qs[3]);
                qs[4]=fmaf(oe,w1.x,qs[4]); qs[5]=fmaf(oe,w1.y,qs[5]);
                qs[6]=fmaf(oe,w1.z,qs[6]); qs[7]=fmaf(oe,w1.w,qs[7]);
            }
        }
        *reinterpret_cast<float4*>(qkb + (size_t)b*64 + g*8)     = make_float4(qs[0],qs[1],qs[2],qs[3]);
        *reinterpret_cast<float4*>(qkb + (size_t)b*64 + g*8 + 4) = make_float4(qs[4],qs[5],qs[6],qs[7]);
    }
}

// ------------------------------------------------------- K2: MFMA neighbors
#define EPW 4   // elements per wave

__global__ __launch_bounds__(256, 2) void actor_neigh(
    const float* __restrict__ s2g, const float* __restrict__ bS1g,
    const float* __restrict__ bS2g, const float* __restrict__ ws,
    float* __restrict__ wsP)
{
    const int lane = threadIdx.x & 63;
    const int wid  = threadIdx.x >> 6;
    const int q    = lane >> 4;
    const int r    = lane & 15;

    // per-wave private H tile: 2 sub-tiles x 16 rows x 72 bf16 (pad: 2-way max)
    __shared__ ushort Hl[4][2 * 16 * 72];

    short8 A1[4], A2[8];
    {
        const short8* p1 = reinterpret_cast<const short8*>(ws + WS_A1F);
        #pragma unroll
        for (int ht = 0; ht < 4; ++ht) A1[ht] = p1[ht * 64 + lane];
        const short8* p2 = reinterpret_cast<const short8*>(ws + WS_A2F);
        #pragma unroll
        for (int f = 0; f < 8; ++f) A2[f] = p2[f * 64 + lane];
    }
    f32x4 b1f[4], b2f[4];
    #pragma unroll
    for (int t4 = 0; t4 < 4; ++t4) {
        b1f[t4] = *reinterpret_cast<const f32x4*>(bS1g + t4 * 16 + q * 4);
        b2f[t4] = *reinterpret_cast<const f32x4*>(bS2g + t4 * 16 + q * 4);
    }
    const float* qkb = ws + WS_QKB;

    const int e0 = (blockIdx.x * 4 + wid) * EPW;

    // prefetch element e0's s2 fragments (per lane: row r of tile t, 8 floats)
    float4 cs[4];
    {
        const float* base = s2g + (size_t)e0 * 512;
        #pragma unroll
        for (int t = 0; t < 2; ++t) {
            const float* sp = base + (t*16 + r)*16 + (q & 1)*8;
            cs[t*2+0] = *reinterpret_cast<const float4*>(sp);
            cs[t*2+1] = *reinterpret_cast<const float4*>(sp + 4);
        }
    }

    #pragma unroll 1
    for (int ei = 0; ei < EPW; ++ei) {
        const int b = e0 + ei;
        float4 ns[4];
        if (ei + 1 < EPW) {
            const float* base = s2g + (size_t)(b + 1) * 512;
            #pragma unroll
            for (int t = 0; t < 2; ++t) {
                const float* sp = base + (t*16 + r)*16 + (q & 1)*8;
                ns[t*2+0] = *reinterpret_cast<const float4*>(sp);
                ns[t*2+1] = *reinterpret_cast<const float4*>(sp + 4);
            }
        }
        f32x4 qkf[4];
        #pragma unroll
        for (int dt = 0; dt < 4; ++dt)
            qkf[dt] = *reinterpret_cast<const f32x4*>(qkb + (size_t)b*64 + dt*16 + q*4);

        f32x4 Pac[4] = {{0,0,0,0},{0,0,0,0},{0,0,0,0},{0,0,0,0}};
        float den = 0.f;
        const f32x4 z = {0.f, 0.f, 0.f, 0.f};

        #pragma unroll
        for (int t = 0; t < 2; ++t) {
            // B1-frag: B[k][n] = s2[sample n][obs k] (k>=16 garbage, A1 zeros kill it)
            union { short8 s8; unsigned u[4]; } B1;
            float4 sa = cs[t*2+0], sb = cs[t*2+1];
            B1.u[0] = pk2(sa.x, sa.y); B1.u[1] = pk2(sa.z, sa.w);
            B1.u[2] = pk2(sb.x, sb.y); B1.u[3] = pk2(sb.z, sb.w);

            // GEMM1: H^T tile = W_s1 @ S2^T
            f32x4 hD[4];
            #pragma unroll
            for (int ht = 0; ht < 4; ++ht)
                hD[ht] = __builtin_amdgcn_mfma_f32_16x16x32_bf16(A1[ht], B1.s8, z, 0, 0, 0);

            // bias+relu, pack bf16, stage to LDS row [sample r][hidden]
            ushort* hrow = &Hl[wid][t * 1152 + r * 72];
            #pragma unroll
            for (int ht = 0; ht < 4; ++ht) {
                float h0 = fmaxf(hD[ht][0] + b1f[ht][0], 0.f);
                float h1 = fmaxf(hD[ht][1] + b1f[ht][1], 0.f);
                float h2 = fmaxf(hD[ht][2] + b1f[ht][2], 0.f);
                float h3 = fmaxf(hD[ht][3] + b1f[ht][3], 0.f);
                *reinterpret_cast<uint2*>(hrow + ht*16 + q*4) =
                    make_uint2(pk2(h0, h1), pk2(h2, h3));
            }
            // B2-frags: B[k][n] = h[sample r][hidden kt*32+q*8+j]
            const ushort* rrow = &Hl[wid][t * 1152 + r * 72];
            short8 B2a = *reinterpret_cast<const short8*>(rrow + 0  + q * 8);
            short8 B2b = *reinterpret_cast<const short8*>(rrow + 32 + q * 8);

            // GEMM2: INTRU^T = W_s2 @ H^T (accumulate 2 k-tiles)
            f32x4 iD[4];
            #pragma unroll
            for (int dt = 0; dt < 4; ++dt) {
                f32x4 c0 = __builtin_amdgcn_mfma_f32_16x16x32_bf16(A2[dt*2+0], B2a, z, 0, 0, 0);
                iD[dt]   = __builtin_amdgcn_mfma_f32_16x16x32_bf16(A2[dt*2+1], B2b, c0, 0, 0, 0);
            }
            // bias + relu + rowsum(mask) + score
            float sc = 0.f, rs = 0.f;
            #pragma unroll
            for (int dt = 0; dt < 4; ++dt) {
                #pragma unroll
                for (int i = 0; i < 4; ++i) {
                    float x = fmaxf(iD[dt][i] + b2f[dt][i], 0.f);
                    iD[dt][i] = x;
                    rs += x;
                    sc = fmaf(x, qkf[dt][i], sc);
                }
            }
            sc += __shfl_xor(sc, 16, 64);
            sc += __shfl_xor(sc, 32, 64);
            rs += __shfl_xor(rs, 16, 64);
            rs += __shfl_xor(rs, 32, 64);
            // scores are O(1e-2): exp without max-subtraction is exact-safe
            float w = (rs != 0.f) ? __expf(sc * 0.125f) : 0.f;
            den += w;
            #pragma unroll
            for (int dt = 0; dt < 4; ++dt)
                #pragma unroll
                for (int i = 0; i < 4; ++i)
                    Pac[dt][i] = fmaf(w, iD[dt][i], Pac[dt][i]);
        }
        // reduce pooled sum + denom across the 16 samples (lane bits 0-3)
        #pragma unroll
        for (int m = 1; m <= 8; m <<= 1) {
            den += __shfl_xor(den, m, 64);
            #pragma unroll
            for (int dt = 0; dt < 4; ++dt)
                #pragma unroll
                for (int i = 0; i < 4; ++i)
                    Pac[dt][i] += __shfl_xor(Pac[dt][i], m, 64);
        }
        float inv = (den > 0.f) ? (1.f / den) : 0.f;   // all-masked -> 0
        if (r == 0) {
            #pragma unroll
            for (int dt = 0; dt < 4; ++dt) {
                f32x4 o = Pac[dt] * inv;
                *reinterpret_cast<f32x4*>(wsP + (size_t)b*64 + dt*16 + q*4) = o;
            }
        }
        if (ei + 1 < EPW) {
            #pragma unroll
            for (int u = 0; u < 4; ++u) cs[u] = ns[u];
        }
    }
}

// ---------------------------------------------------------------- K3: tail
__global__ __launch_bounds__(256, 2) void actor_tail(
    const float* __restrict__ s0g, const float* __restrict__ s1g,
    const float* __restrict__ bOwn, const float* __restrict__ bEnv,
    const float* __restrict__ wV,   const float* __restrict__ bMo,
    const float* __restrict__ bA1,  const float* __restrict__ wA2,
    const float* __restrict__ bA2,  const float* __restrict__ ws,
    const float* __restrict__ wsP,  float* __restrict__ outg)
{
    const float* __restrict__ wOwnT  = ws + WS_OWNT;
    const float* __restrict__ wFoldT = ws + WS_FOLDT;
    const float* __restrict__ wA1T   = ws + WS_A1T;
    const float* __restrict__ wEnvT  = ws + WS_ENVT;

    __shared__ float concatL[32][196];
    const int tid = threadIdx.x;
    const int el = tid >> 3, g = tid & 7;
    const int b = blockIdx.x * 32 + el;

    // own_e -> concatL[0..63]
    float s0r[16];
    {
        const float4* p = reinterpret_cast<const float4*>(s0g + (size_t)b * 16);
        #pragma unroll
        for (int qq = 0; qq < 4; ++qq) {
            float4 v = p[qq];
            s0r[qq*4+0]=v.x; s0r[qq*4+1]=v.y; s0r[qq*4+2]=v.z; s0r[qq*4+3]=v.w;
        }
    }
    {
        float4 b0 = *reinterpret_cast<const float4*>(bOwn + g*8);
        float4 b1 = *reinterpret_cast<const float4*>(bOwn + g*8 + 4);
        float ow[8] = {b0.x,b0.y,b0.z,b0.w,b1.x,b1.y,b1.z,b1.w};
        #pragma unroll
        for (int k = 0; k < 16; ++k) {
            float sk = s0r[k];
            const float* wr = wOwnT + k*64 + g*8;
            float4 w0 = *reinterpret_cast<const float4*>(wr);
            float4 w1 = *reinterpret_cast<const float4*>(wr + 4);
            ow[0]=fmaf(sk,w0.x,ow[0]); ow[1]=fmaf(sk,w0.y,ow[1]);
            ow[2]=fmaf(sk,w0.z,ow[2]); ow[3]=fmaf(sk,w0.w,ow[3]);
            ow[4]=fmaf(sk,w1.x,ow[4]); ow[5]=fmaf(sk,w1.y,ow[5]);
            ow[6]=fmaf(sk,w1.z,ow[6]); ow[7]=fmaf(sk,w1.w,ow[7]);
        }
        #pragma unroll
        for (int j = 0; j < 8; ++j) ow[j] = fmaxf(ow[j], 0.f);
        *reinterpret_cast<float4*>(&concatL[el][g*8])     = make_float4(ow[0],ow[1],ow[2],ow[3]);
        *reinterpret_cast<float4*>(&concatL[el][g*8 + 4]) = make_float4(ow[4],ow[5],ow[6],ow[7]);
    }

    // env_e -> concatL[64..127]
    {
        float4 b0 = *reinterpret_cast<const float4*>(bEnv + g*8);
        float4 b1 = *reinterpret_cast<const float4*>(bEnv + g*8 + 4);
        float ev[8] = {b0.x,b0.y,b0.z,b0.w,b1.x,b1.y,b1.z,b1.w};
        const float* s1b = s1g + (size_t)b * 64;
        #pragma unroll 2
        for (int k4 = 0; k4 < 16; ++k4) {
            float4 sv = *reinterpret_cast<const float4*>(s1b + k4*4);
            #pragma unroll
            for (int qq = 0; qq < 4; ++qq) {
                float sk = (qq==0)?sv.x:(qq==1)?sv.y:(qq==2)?sv.z:sv.w;
                const float* wr = wEnvT + (k4*4+qq)*64 + g*8;
                float4 w0 = *reinterpret_cast<const float4*>(wr);
                float4 w1 = *reinterpret_cast<const float4*>(wr + 4);
                ev[0]=fmaf(sk,w0.x,ev[0]); ev[1]=fmaf(sk,w0.y,ev[1]);
                ev[2]=fmaf(sk,w0.z,ev[2]); ev[3]=fmaf(sk,w0.w,ev[3]);
                ev[4]=fmaf(sk,w1.x,ev[4]); ev[5]=fmaf(sk,w1.y,ev[5]);
                ev[6]=fmaf(sk,w1.z,ev[6]); ev[7]=fmaf(sk,w1.w,ev[7]);
            }
        }
        #pragma unroll
        for (int j = 0; j < 8; ++j) ev[j] = fmaxf(ev[j], 0.f);
        *reinterpret_cast<float4*>(&concatL[el][64 + g*8])     = make_float4(ev[0],ev[1],ev[2],ev[3]);
        *reinterpret_cast<float4*>(&concatL[el][64 + g*8 + 4]) = make_float4(ev[4],ev[5],ev[6],ev[7]);
    }

    // v_att = P @ W_v^T -> concatL[128..191]
    {
        float Pv[64];
        {
            const float4* pp = reinterpret_cast<const float4*>(wsP + (size_t)b * 64);
            #pragma unroll
            for (int d4 = 0; d4 < 16; ++d4) {
                float4 v = pp[d4];
                Pv[d4*4+0]=v.x; Pv[d4*4+1]=v.y; Pv[d4*4+2]=v.z; Pv[d4*4+3]=v.w;
            }
        }
        float va[8];
        #pragma unroll
        for (int jj = 0; jj < 8; ++jj) {
            const float* wr = wV + (g*8 + jj)*64;
            float a0=0,a1=0,a2=0,a3=0;
            #pragma unroll
            for (int dp = 0; dp < 64; dp += 4) {
                float4 w4 = *reinterpret_cast<const float4*>(wr + dp);
                a0 = fmaf(Pv[dp+0], w4.x, a0);
                a1 = fmaf(Pv[dp+1], w4.y, a1);
                a2 = fmaf(Pv[dp+2], w4.z, a2);
                a3 = fmaf(Pv[dp+3], w4.w, a3);
            }
            va[jj] = (a0+a1)+(a2+a3);
        }
        *reinterpret_cast<float4*>(&concatL[el][128 + g*8])     = make_float4(va[0],va[1],va[2],va[3]);
        *reinterpret_cast<float4*>(&concatL[el][128 + g*8 + 4]) = make_float4(va[4],va[5],va[6],va[7]);
    }

    // mo = concat @ W_fold^T + b_mo (wave-local RAW on concatL)
    float mo[16];
    {
        const float* bm = bMo + g*16;
        #pragma unroll
        for (int qq = 0; qq < 4; ++qq) {
            float4 v = *reinterpret_cast<const float4*>(bm + qq*4);
            mo[qq*4+0]=v.x; mo[qq*4+1]=v.y; mo[qq*4+2]=v.z; mo[qq*4+3]=v.w;
        }
    }
    #pragma unroll 2
    for (int i4 = 0; i4 < 48; ++i4) {
        float4 c4 = *reinterpret_cast<const float4*>(&concatL[el][i4*4]);
        #pragma unroll
        for (int qq = 0; qq < 4; ++qq) {
            float ci = (qq==0)?c4.x:(qq==1)?c4.y:(qq==2)?c4.z:c4.w;
            const float* wr = wFoldT + (i4*4+qq)*128 + g*16;
            #pragma unroll
            for (int u = 0; u < 4; ++u) {
                float4 w4 = *reinterpret_cast<const float4*>(wr + u*4);
                mo[u*4+0]=fmaf(ci,w4.x,mo[u*4+0]);
                mo[u*4+1]=fmaf(ci,w4.y,mo[u*4+1]);
                mo[u*4+2]=fmaf(ci,w4.z,mo[u*4+2]);
                mo[u*4+3]=fmaf(ci,w4.w,mo[u*4+3]);
            }
        }
    }
    #pragma unroll
    for (int qq = 0; qq < 4; ++qq)
        *reinterpret_cast<float4*>(&concatL[el][g*16 + qq*4]) =
            make_float4(mo[qq*4],mo[qq*4+1],mo[qq*4+2],mo[qq*4+3]);

    // a = relu(mo @ W_a1^T + b_a1)
    float av[8];
    {
        float4 b0 = *reinterpret_cast<const float4*>(bA1 + g*8);
        float4 b1 = *reinterpret_cast<const float4*>(bA1 + g*8 + 4);
        av[0]=b0.x; av[1]=b0.y; av[2]=b0.z; av[3]=b0.w;
        av[4]=b1.x; av[5]=b1.y; av[6]=b1.z; av[7]=b1.w;
    }
    #pragma unroll 2
    for (int j4 = 0; j4 < 32; ++j4) {
        float4 m4 = *reinterpret_cast<const float4*>(&concatL[el][j4*4]);
        #pragma unroll
        for (int qq = 0; qq < 4; ++qq) {
            float mj = (qq==0)?m4.x:(qq==1)?m4.y:(qq==2)?m4.z:m4.w;
            const float* wr = wA1T + (j4*4+qq)*64 + g*8;
            float4 w0 = *reinterpret_cast<const float4*>(wr);
            float4 w1 = *reinterpret_cast<const float4*>(wr + 4);
            av[0]=fmaf(mj,w0.x,av[0]); av[1]=fmaf(mj,w0.y,av[1]);
            av[2]=fmaf(mj,w0.z,av[2]); av[3]=fmaf(mj,w0.w,av[3]);
            av[4]=fmaf(mj,w1.x,av[4]); av[5]=fmaf(mj,w1.y,av[5]);
            av[6]=fmaf(mj,w1.z,av[6]); av[7]=fmaf(mj,w1.w,av[7]);
        }
    }
    #pragma unroll
    for (int j = 0; j < 8; ++j) av[j] = fmaxf(av[j], 0.f);

    // out = tanh(a @ W_a2^T + b_a2)
    {
        float4 w0a = *reinterpret_cast<const float4*>(wA2 + g*8);
        float4 w0b = *reinterpret_cast<const float4*>(wA2 + g*8 + 4);
        float4 w1a = *reinterpret_cast<const float4*>(wA2 + 64 + g*8);
        float4 w1b = *reinterpret_cast<const float4*>(wA2 + 64 + g*8 + 4);
        float p0 = av[0]*w0a.x + av[1]*w0a.y + av[2]*w0a.z + av[3]*w0a.w
                 + av[4]*w0b.x + av[5]*w0b.y + av[6]*w0b.z + av[7]*w0b.w;
        float p1 = av[0]*w1a.x + av[1]*w1a.y + av[2]*w1a.z + av[3]*w1a.w
                 + av[4]*w1b.x + av[5]*w1b.y + av[6]*w1b.z + av[7]*w1b.w;
        #pragma unroll
        for (int msk = 1; msk <= 4; msk <<= 1) {
            p0 += __shfl_xor(p0, msk, 64);
            p1 += __shfl_xor(p1, msk, 64);
        }
        if (g == 0) {
            float o0 = tanhf(p0 + bA2[0]);
            float o1 = tanhf(p1 + bA2[1]);
            *reinterpret_cast<float2*>(outg + (size_t)b * 2) = make_float2(o0, o1);
        }
    }
}

extern "C" void kernel_launch(void* const* d_in, const int* in_sizes, int n_in,
                              void* d_out, int out_size, void* d_ws, size_t ws_size,
                              hipStream_t stream) {
    const float* s0   = (const float*)d_in[0];
    const float* s1   = (const float*)d_in[1];
    const float* s2   = (const float*)d_in[2];
    const float* wOwn = (const float*)d_in[3];
    const float* bOwn = (const float*)d_in[4];
    const float* wEnv = (const float*)d_in[5];
    const float* bEnv = (const float*)d_in[6];
    const float* wS1  = (const float*)d_in[7];
    const float* bS1  = (const float*)d_in[8];
    const float* wS2  = (const float*)d_in[9];
    const float* bS2  = (const float*)d_in[10];
    const float* wQ   = (const float*)d_in[11];
    const float* wK   = (const float*)d_in[12];
    const float* wV   = (const float*)d_in[13];
    // d_in[14] (W_cq) / d_in[15] (W_ck): dead code in the reference.
    const float* wCv  = (const float*)d_in[16];
    const float* wMo  = (const float*)d_in[17];
    const float* bMo  = (const float*)d_in[18];
    const float* wA1  = (const float*)d_in[19];
    const float* bA1  = (const float*)d_in[20];
    const float* wA2  = (const float*)d_in[21];
    const float* bA2  = (const float*)d_in[22];
    float* ws  = (float*)d_ws;
    float* out = (float*)d_out;

    hipLaunchKernelGGL(actor_setup, dim3(WS_WEND / 256), dim3(256), 0, stream,
                       wOwn, wEnv, wS1, wS2, wQ, wK, wCv, wMo, wA1, ws);
    hipLaunchKernelGGL(actor_pre, dim3(16384 / 32), dim3(256), 0, stream,
                       s0, bOwn, ws, ws + WS_QKB);
    hipLaunchKernelGGL(actor_neigh, dim3(16384 / (4 * EPW)), dim3(256), 0, stream,
                       s2, bS1, bS2, ws, ws + WS_P);
    hipLaunchKernelGGL(actor_tail, dim3(16384 / 32), dim3(256), 0, stream,
                       s0, s1, bOwn, bEnv, wV, bMo, bA1, wA2, bA2,
                       ws, ws + WS_P, out);
}

// Round 4
// 81.609 us; speedup vs baseline: 3.9264x; 2.2836x over previous
//
#include <hip/hip_runtime.h>
#include <math.h>

// ---------------------------------------------------------------------------
// ActorNetwork, round 4: MFMA tail (mo, a1) + in-K2 v_att projection.
//
// Exact algebraic folds: W_cq/W_ck dead; score via wQK = W_q^T W_k;
// pool-then-project for W_v (projection now fused into K2);
// W_fold = blockdiag fold of W_mo,W_cv (bf16 A-frags).
//
// Round-4 changes (theory: tail was latency-bound, 145us, VALUBusy 8.8%,
// per-lane global re-reads of 98KB wFoldT at 8 waves/CU):
//   * K3 rewritten: mo/a1 GEMMs on mfma_f32_16x16x32_bf16 with
//     register-resident weight frags (loaded once per block). X staged in
//     LDS with (row&7)<<4 XOR swizzle (T2) for conflict-free b128 reads.
//   * X = [own_e|env_e|v_att|qk] bf16 rows (512B) in ws: K1 writes own/env/qk,
//     K2 writes v_att (P broadcast in-wave after xor-reduce, 64 FMA/lane).
//   * ws footprint 8.5MB (== r3's proven-safe 8.6MB).
// ---------------------------------------------------------------------------

typedef __attribute__((ext_vector_type(8))) short short8;
typedef __attribute__((ext_vector_type(4))) float f32x4;

// ws layout (4-byte units)
#define WS_A1F   0        // [4 ht][256]   bf16 A-frags W_s1 (K=16 padded to 32)
#define WS_A2F   1024     // [8 f][256]    bf16 A-frags W_s2
#define WS_QK    3072     // [64][64] f32  W_q^T @ W_k
#define WS_FOLDF 7168     // [48 f][256]   bf16 A-frags W_fold (8 RT x 6 kt)
#define WS_A1FR  19456    // [16 f][256]   bf16 A-frags W_a1 (4 rt x 4 kt)
#define WS_ENVT  23552    // [64][64] f32  W_env^T
#define WS_OWNT  27648    // [16][64] f32  W_own^T
#define WS_WEND  28672
#define WS_XBU   28672    // [16384][128] uint = [16384][256] bf16 X rows:
                          //   [0:64 own | 64:128 env | 128:192 vatt | 192:256 qk]

static __device__ inline unsigned short f2bf(float x) {
    union { float f; unsigned u; } c; c.f = x;
    unsigned r = c.u + 0x7fff + ((c.u >> 16) & 1);   // RNE
    return (unsigned short)(r >> 16);
}
static __device__ inline unsigned pk2(float a, float b) {
    return (unsigned)f2bf(a) | ((unsigned)f2bf(b) << 16);
}
static __device__ inline float bflo(unsigned u) {
    union { unsigned x; float f; } c; c.x = u << 16; return c.f;
}
static __device__ inline float bfhi(unsigned u) {
    union { unsigned x; float f; } c; c.x = u & 0xffff0000u; return c.f;
}

// ---------------------------------------------------------------- K0: setup
__global__ void actor_setup(
    const float* __restrict__ wOwn, const float* __restrict__ wEnv,
    const float* __restrict__ wS1,  const float* __restrict__ wS2,
    const float* __restrict__ wQ,   const float* __restrict__ wK,
    const float* __restrict__ wCv,  const float* __restrict__ wMo,
    const float* __restrict__ wA1,  float* __restrict__ ws)
{
    int t = blockIdx.x * 256 + threadIdx.x;
    unsigned* wsu = reinterpret_cast<unsigned*>(ws);
    if (t < 1024) {                        // A1F: A[m][k]=W_s1[ht*16+m][k], k<16 else 0
        int ht = t >> 8, rem = t & 255, lane = rem >> 2, jj = rem & 3;
        int q = lane >> 4, m = lane & 15;
        int row = ht * 16 + m, k0 = q * 8 + jj * 2;
        float v0 = (k0 < 16) ? wS1[row * 16 + k0]     : 0.f;
        float v1 = (k0 < 16) ? wS1[row * 16 + k0 + 1] : 0.f;
        wsu[WS_A1F + t] = pk2(v0, v1);
    } else if (t < 3072) {                 // A2F: A[m][k]=W_s2[dt*16+m][kt*32+k]
        int u = t - 1024;
        int f = u >> 8, rem = u & 255, lane = rem >> 2, jj = rem & 3;
        int q = lane >> 4, m = lane & 15;
        int dt = f >> 1, kt = f & 1;
        int row = dt * 16 + m, k = kt * 32 + q * 8 + jj * 2;
        wsu[WS_A2F + u] = pk2(wS2[row * 64 + k], wS2[row * 64 + k + 1]);
    } else if (t < 7168) {                 // wQK[e][dp]
        int u = t - 3072; int e = u >> 6, dp = u & 63;
        float acc = 0.f;
        for (int d = 0; d < 64; ++d) acc += wQ[d * 64 + e] * wK[d * 64 + dp];
        ws[WS_QK + u] = acc;
    } else if (t < 19456) {                // FOLDF: W_fold[RT*16+m][kt*32+...] bf16 frags
        int u = t - 7168;
        int f = u >> 8, rem = u & 255, lane = rem >> 2, jj = rem & 3;
        int RT = f / 6, kt = f - RT * 6;
        int row = RT * 16 + (lane & 15);
        int k = kt * 32 + (lane >> 4) * 8 + jj * 2;
        int h = k >> 6, dp = k & 63;
        const float* wmr = wMo + row * 192 + h * 64;
        float a0 = 0.f, a1 = 0.f;
        for (int d = 0; d < 64; ++d) {
            float m = wmr[d];
            a0 = fmaf(m, wCv[d * 64 + dp],     a0);
            a1 = fmaf(m, wCv[d * 64 + dp + 1], a1);
        }
        wsu[WS_FOLDF + u] = pk2(a0, a1);
    } else if (t < 23552) {                // A1FR: W_a1[rt*16+m][kt*32+...] bf16 frags
        int u = t - 19456;
        int f = u >> 8, rem = u & 255, lane = rem >> 2, jj = rem & 3;
        int rt = f >> 2, kt = f & 3;
        int row = rt * 16 + (lane & 15);
        int k = kt * 32 + (lane >> 4) * 8 + jj * 2;
        wsu[WS_A1FR + u] = pk2(wA1[row * 128 + k], wA1[row * 128 + k + 1]);
    } else if (t < 27648) {                // wEnvT[k][d]
        int u = t - 23552; int k = u >> 6, d = u & 63;
        ws[WS_ENVT + u] = wEnv[d * 64 + k];
    } else if (t < WS_WEND) {              // wOwnT[k][d]
        int u = t - 27648; int k = u >> 6, d = u & 63;
        ws[WS_OWNT + u] = wOwn[d * 16 + k];
    }
}

// ----------------------------------------------- K1: own_e, env_e, qk -> X
__global__ __launch_bounds__(256) void actor_pre(
    const float* __restrict__ s0g, const float* __restrict__ s1g,
    const float* __restrict__ bOwn, const float* __restrict__ bEnv,
    const float* __restrict__ ws,   unsigned* __restrict__ xbu)
{
    const float* __restrict__ wOwnT = ws + WS_OWNT;
    const float* __restrict__ wQK   = ws + WS_QK;
    const float* __restrict__ wEnvT = ws + WS_ENVT;
    __shared__ float ownL[32][68];
    const int tid = threadIdx.x;
    const int el = tid >> 3, g = tid & 7;
    const int b = blockIdx.x * 32 + el;
    unsigned* xrow = xbu + (size_t)b * 128;

    // own_e
    float s0r[16];
    {
        const float4* p = reinterpret_cast<const float4*>(s0g + (size_t)b * 16);
        #pragma unroll
        for (int qq = 0; qq < 4; ++qq) {
            float4 v = p[qq];
            s0r[qq*4+0]=v.x; s0r[qq*4+1]=v.y; s0r[qq*4+2]=v.z; s0r[qq*4+3]=v.w;
        }
    }
    {
        float4 b0 = *reinterpret_cast<const float4*>(bOwn + g*8);
        float4 b1 = *reinterpret_cast<const float4*>(bOwn + g*8 + 4);
        float ow[8] = {b0.x,b0.y,b0.z,b0.w,b1.x,b1.y,b1.z,b1.w};
        #pragma unroll
        for (int k = 0; k < 16; ++k) {
            float sk = s0r[k];
            const float* wr = wOwnT + k*64 + g*8;
            float4 w0 = *reinterpret_cast<const float4*>(wr);
            float4 w1 = *reinterpret_cast<const float4*>(wr + 4);
            ow[0]=fmaf(sk,w0.x,ow[0]); ow[1]=fmaf(sk,w0.y,ow[1]);
            ow[2]=fmaf(sk,w0.z,ow[2]); ow[3]=fmaf(sk,w0.w,ow[3]);
            ow[4]=fmaf(sk,w1.x,ow[4]); ow[5]=fmaf(sk,w1.y,ow[5]);
            ow[6]=fmaf(sk,w1.z,ow[6]); ow[7]=fmaf(sk,w1.w,ow[7]);
        }
        #pragma unroll
        for (int j = 0; j < 8; ++j) ow[j] = fmaxf(ow[j], 0.f);
        *reinterpret_cast<float4*>(&ownL[el][g*8])     = make_float4(ow[0],ow[1],ow[2],ow[3]);
        *reinterpret_cast<float4*>(&ownL[el][g*8 + 4]) = make_float4(ow[4],ow[5],ow[6],ow[7]);
        reinterpret_cast<uint4*>(xrow)[g] =
            make_uint4(pk2(ow[0],ow[1]), pk2(ow[2],ow[3]), pk2(ow[4],ow[5]), pk2(ow[6],ow[7]));
    }

    // qk = own_e @ wQK (same-wave RAW on ownL; no barrier)
    {
        float qs[8] = {0,0,0,0,0,0,0,0};
        #pragma unroll 2
        for (int e4 = 0; e4 < 16; ++e4) {
            float4 c4 = *reinterpret_cast<const float4*>(&ownL[el][e4*4]);
            #pragma unroll
            for (int qq = 0; qq < 4; ++qq) {
                float oe = (qq==0)?c4.x:(qq==1)?c4.y:(qq==2)?c4.z:c4.w;
                const float* wr = wQK + (e4*4+qq)*64 + g*8;
                float4 w0 = *reinterpret_cast<const float4*>(wr);
                float4 w1 = *reinterpret_cast<const float4*>(wr + 4);
                qs[0]=fmaf(oe,w0.x,qs[0]); qs[1]=fmaf(oe,w0.y,qs[1]);
                qs[2]=fmaf(oe,w0.z,qs[2]); qs[3]=fmaf(oe,w0.w,qs[3]);
                qs[4]=fmaf(oe,w1.x,qs[4]); qs[5]=fmaf(oe,w1.y,qs[5]);
                qs[6]=fmaf(oe,w1.z,qs[6]); qs[7]=fmaf(oe,w1.w,qs[7]);
            }
        }
        reinterpret_cast<uint4*>(xrow + 96)[g] =
            make_uint4(pk2(qs[0],qs[1]), pk2(qs[2],qs[3]), pk2(qs[4],qs[5]), pk2(qs[6],qs[7]));
    }

    // env_e
    {
        float4 b0 = *reinterpret_cast<const float4*>(bEnv + g*8);
        float4 b1 = *reinterpret_cast<const float4*>(bEnv + g*8 + 4);
        float ev[8] = {b0.x,b0.y,b0.z,b0.w,b1.x,b1.y,b1.z,b1.w};
        const float* s1b = s1g + (size_t)b * 64;
        #pragma unroll 2
        for (int k4 = 0; k4 < 16; ++k4) {
            float4 sv = *reinterpret_cast<const float4*>(s1b + k4*4);
            #pragma unroll
            for (int qq = 0; qq < 4; ++qq) {
                float sk = (qq==0)?sv.x:(qq==1)?sv.y:(qq==2)?sv.z:sv.w;
                const float* wr = wEnvT + (k4*4+qq)*64 + g*8;
                float4 w0 = *reinterpret_cast<const float4*>(wr);
                float4 w1 = *reinterpret_cast<const float4*>(wr + 4);
                ev[0]=fmaf(sk,w0.x,ev[0]); ev[1]=fmaf(sk,w0.y,ev[1]);
                ev[2]=fmaf(sk,w0.z,ev[2]); ev[3]=fmaf(sk,w0.w,ev[3]);
                ev[4]=fmaf(sk,w1.x,ev[4]); ev[5]=fmaf(sk,w1.y,ev[5]);
                ev[6]=fmaf(sk,w1.z,ev[6]); ev[7]=fmaf(sk,w1.w,ev[7]);
            }
        }
        #pragma unroll
        for (int j = 0; j < 8; ++j) ev[j] = fmaxf(ev[j], 0.f);
        reinterpret_cast<uint4*>(xrow + 32)[g] =
            make_uint4(pk2(ev[0],ev[1]), pk2(ev[2],ev[3]), pk2(ev[4],ev[5]), pk2(ev[6],ev[7]));
    }
}

// ------------------------------------------------------- K2: MFMA neighbors
#define EPW 4   // elements per wave

__global__ __launch_bounds__(256, 2) void actor_neigh(
    const float* __restrict__ s2g, const float* __restrict__ bS1g,
    const float* __restrict__ bS2g, const float* __restrict__ wV,
    const float* __restrict__ ws,   unsigned* __restrict__ xbu)
{
    const int lane = threadIdx.x & 63;
    const int wid  = threadIdx.x >> 6;
    const int q    = lane >> 4;
    const int r    = lane & 15;

    __shared__ ushort Hl[4][2 * 16 * 72];
    __shared__ float  PL[4][68];

    short8 A1[4], A2[8];
    {
        const short8* p1 = reinterpret_cast<const short8*>(ws + WS_A1F);
        #pragma unroll
        for (int ht = 0; ht < 4; ++ht) A1[ht] = p1[ht * 64 + lane];
        const short8* p2 = reinterpret_cast<const short8*>(ws + WS_A2F);
        #pragma unroll
        for (int f = 0; f < 8; ++f) A2[f] = p2[f * 64 + lane];
    }
    f32x4 b1f[4], b2f[4];
    #pragma unroll
    for (int t4 = 0; t4 < 4; ++t4) {
        b1f[t4] = *reinterpret_cast<const f32x4*>(bS1g + t4 * 16 + q * 4);
        b2f[t4] = *reinterpret_cast<const f32x4*>(bS2g + t4 * 16 + q * 4);
    }

    const int e0 = (blockIdx.x * 4 + wid) * EPW;

    float4 cs[4];
    {
        const float* base = s2g + (size_t)e0 * 512;
        #pragma unroll
        for (int t = 0; t < 2; ++t) {
            const float* sp = base + (t*16 + r)*16 + (q & 1)*8;
            cs[t*2+0] = *reinterpret_cast<const float4*>(sp);
            cs[t*2+1] = *reinterpret_cast<const float4*>(sp + 4);
        }
    }

    #pragma unroll 1
    for (int ei = 0; ei < EPW; ++ei) {
        const int b = e0 + ei;
        float4 ns[4];
        if (ei + 1 < EPW) {
            const float* base = s2g + (size_t)(b + 1) * 512;
            #pragma unroll
            for (int t = 0; t < 2; ++t) {
                const float* sp = base + (t*16 + r)*16 + (q & 1)*8;
                ns[t*2+0] = *reinterpret_cast<const float4*>(sp);
                ns[t*2+1] = *reinterpret_cast<const float4*>(sp + 4);
            }
        }
        // qk (bf16) for this element
        f32x4 qkf[4];
        {
            const unsigned* qrow = xbu + (size_t)b * 128 + 96;
            #pragma unroll
            for (int dt = 0; dt < 4; ++dt) {
                unsigned u0 = qrow[dt*8 + q*2];
                unsigned u1 = qrow[dt*8 + q*2 + 1];
                qkf[dt][0] = bflo(u0); qkf[dt][1] = bfhi(u0);
                qkf[dt][2] = bflo(u1); qkf[dt][3] = bfhi(u1);
            }
        }

        f32x4 Pac[4] = {{0,0,0,0},{0,0,0,0},{0,0,0,0},{0,0,0,0}};
        float den = 0.f;
        const f32x4 z = {0.f, 0.f, 0.f, 0.f};

        #pragma unroll
        for (int t = 0; t < 2; ++t) {
            union { short8 s8; unsigned u[4]; } B1;
            float4 sa = cs[t*2+0], sb = cs[t*2+1];
            B1.u[0] = pk2(sa.x, sa.y); B1.u[1] = pk2(sa.z, sa.w);
            B1.u[2] = pk2(sb.x, sb.y); B1.u[3] = pk2(sb.z, sb.w);

            f32x4 hD[4];
            #pragma unroll
            for (int ht = 0; ht < 4; ++ht)
                hD[ht] = __builtin_amdgcn_mfma_f32_16x16x32_bf16(A1[ht], B1.s8, z, 0, 0, 0);

            ushort* hrow = &Hl[wid][t * 1152 + r * 72];
            #pragma unroll
            for (int ht = 0; ht < 4; ++ht) {
                float h0 = fmaxf(hD[ht][0] + b1f[ht][0], 0.f);
                float h1 = fmaxf(hD[ht][1] + b1f[ht][1], 0.f);
                float h2 = fmaxf(hD[ht][2] + b1f[ht][2], 0.f);
                float h3 = fmaxf(hD[ht][3] + b1f[ht][3], 0.f);
                *reinterpret_cast<uint2*>(hrow + ht*16 + q*4) =
                    make_uint2(pk2(h0, h1), pk2(h2, h3));
            }
            const ushort* rrow = &Hl[wid][t * 1152 + r * 72];
            short8 B2a = *reinterpret_cast<const short8*>(rrow + 0  + q * 8);
            short8 B2b = *reinterpret_cast<const short8*>(rrow + 32 + q * 8);

            f32x4 iD[4];
            #pragma unroll
            for (int dt = 0; dt < 4; ++dt) {
                f32x4 c0 = __builtin_amdgcn_mfma_f32_16x16x32_bf16(A2[dt*2+0], B2a, z, 0, 0, 0);
                iD[dt]   = __builtin_amdgcn_mfma_f32_16x16x32_bf16(A2[dt*2+1], B2b, c0, 0, 0, 0);
            }
            float sc = 0.f, rs = 0.f;
            #pragma unroll
            for (int dt = 0; dt < 4; ++dt) {
                #pragma unroll
                for (int i = 0; i < 4; ++i) {
                    float x = fmaxf(iD[dt][i] + b2f[dt][i], 0.f);
                    iD[dt][i] = x;
                    rs += x;
                    sc = fmaf(x, qkf[dt][i], sc);
                }
            }
            sc += __shfl_xor(sc, 16, 64);
            sc += __shfl_xor(sc, 32, 64);
            rs += __shfl_xor(rs, 16, 64);
            rs += __shfl_xor(rs, 32, 64);
            float w = (rs != 0.f) ? __expf(sc * 0.125f) : 0.f;  // scores O(1e-2)
            den += w;
            #pragma unroll
            for (int dt = 0; dt < 4; ++dt)
                #pragma unroll
                for (int i = 0; i < 4; ++i)
                    Pac[dt][i] = fmaf(w, iD[dt][i], Pac[dt][i]);
        }
        #pragma unroll
        for (int m = 1; m <= 8; m <<= 1) {
            den += __shfl_xor(den, m, 64);
            #pragma unroll
            for (int dt = 0; dt < 4; ++dt)
                #pragma unroll
                for (int i = 0; i < 4; ++i)
                    Pac[dt][i] += __shfl_xor(Pac[dt][i], m, 64);
        }
        float inv = (den > 0.f) ? (1.f / den) : 0.f;   // all-masked -> 0
        if (r == 0) {
            #pragma unroll
            for (int dt = 0; dt < 4; ++dt) {
                f32x4 o = Pac[dt] * inv;
                *reinterpret_cast<f32x4*>(&PL[wid][dt*16 + q*4]) = o;
            }
        }
        // v_att[j], j = lane (same-wave RAW on PL; wV row L1-resident)
        {
            float va = 0.f;
            const float* wvr = wV + lane * 64;
            #pragma unroll
            for (int d4 = 0; d4 < 16; ++d4) {
                float4 p4 = *reinterpret_cast<const float4*>(&PL[wid][d4*4]);
                float4 w4 = *reinterpret_cast<const float4*>(wvr + d4*4);
                va = fmaf(p4.x,w4.x, fmaf(p4.y,w4.y, fmaf(p4.z,w4.z, fmaf(p4.w,w4.w, va))));
            }
            reinterpret_cast<ushort*>(xbu + (size_t)b * 128 + 64)[lane] = f2bf(va);
        }
        if (ei + 1 < EPW) {
            #pragma unroll
            for (int u = 0; u < 4; ++u) cs[u] = ns[u];
        }
    }
}

// ------------------------------------------------ K3: MFMA tail (mo,a1,a2)
__global__ __launch_bounds__(256) void actor_tail(
    const float* __restrict__ bMo, const float* __restrict__ bA1,
    const float* __restrict__ wA2, const float* __restrict__ bA2,
    const float* __restrict__ ws,  const unsigned* __restrict__ xbu,
    float* __restrict__ outg)
{
    const unsigned* wsu = reinterpret_cast<const unsigned*>(ws);
    __shared__ char  xbL[32 * 512];   // X rows, bf16, XOR-swizzled
    __shared__ char  mbL[32 * 256];   // mo rows, bf16, XOR-swizzled
    __shared__ float aL[32][66];      // a rows, fp32
    __shared__ float wA2L[128];

    const int tid  = threadIdx.x;
    const int w    = tid >> 6;
    const int lane = tid & 63;
    const int q    = lane >> 4;
    const int sl   = lane & 15;
    const int swz  = (sl & 7) << 4;
    const int b0   = blockIdx.x * 32;

    // weight frags (once per block; register-resident)
    short8 Amo[2][6], Aa1[4];
    {
        const short8* fp = reinterpret_cast<const short8*>(wsu + WS_FOLDF);
        #pragma unroll
        for (int rt = 0; rt < 2; ++rt)
            #pragma unroll
            for (int kt = 0; kt < 6; ++kt)
                Amo[rt][kt] = fp[((w*2 + rt)*6 + kt)*64 + lane];
        const short8* ap = reinterpret_cast<const short8*>(wsu + WS_A1FR);
        #pragma unroll
        for (int kt = 0; kt < 4; ++kt)
            Aa1[kt] = ap[(w*4 + kt)*64 + lane];
    }

    // Phase A: stage X[0:192] bf16 into swizzled XB
    {
        const int s = tid & 31, j = tid >> 5;   // j 0..7
        const uint4* xrow = reinterpret_cast<const uint4*>(xbu + (size_t)(b0 + s) * 128);
        #pragma unroll
        for (int i = 0; i < 3; ++i) {
            int c = j*3 + i;                    // 16B chunk 0..23
            uint4 v = xrow[c];
            *reinterpret_cast<uint4*>(xbL + s*512 + ((c*16) ^ ((s & 7) << 4))) = v;
        }
        if (tid < 32)
            reinterpret_cast<float4*>(wA2L)[tid] =
                reinterpret_cast<const float4*>(wA2)[tid];
    }
    __syncthreads();

    const f32x4 z = {0.f, 0.f, 0.f, 0.f};

    // Phase B: mo = X @ W_fold^T + b_mo -> MB (bf16)
    #pragma unroll
    for (int st = 0; st < 2; ++st) {
        const int ss = st*16 + sl;
        short8 Bf[6];
        #pragma unroll
        for (int kt = 0; kt < 6; ++kt)
            Bf[kt] = *reinterpret_cast<const short8*>(
                xbL + ss*512 + ((kt*64 + q*16) ^ swz));
        #pragma unroll
        for (int rt = 0; rt < 2; ++rt) {
            f32x4 D = z;
            #pragma unroll
            for (int kt = 0; kt < 6; ++kt)
                D = __builtin_amdgcn_mfma_f32_16x16x32_bf16(Amo[rt][kt], Bf[kt], D, 0, 0, 0);
            f32x4 bm = *reinterpret_cast<const f32x4*>(bMo + w*32 + rt*16 + q*4);
            char* wp = mbL + ss*256 + ((w*64 + rt*32 + q*8) ^ swz);
            *reinterpret_cast<unsigned*>(wp)     = pk2(D[0]+bm[0], D[1]+bm[1]);
            *reinterpret_cast<unsigned*>(wp + 4) = pk2(D[2]+bm[2], D[3]+bm[3]);
        }
    }
    __syncthreads();

    // Phase C: a = relu(mo @ W_a1^T + b_a1) -> aL (fp32)
    #pragma unroll
    for (int st = 0; st < 2; ++st) {
        const int ss = st*16 + sl;
        f32x4 D = z;
        #pragma unroll
        for (int kt = 0; kt < 4; ++kt) {
            short8 Bk = *reinterpret_cast<const short8*>(
                mbL + ss*256 + ((kt*64 + q*16) ^ swz));
            D = __builtin_amdgcn_mfma_f32_16x16x32_bf16(Aa1[kt], Bk, D, 0, 0, 0);
        }
        f32x4 ba = *reinterpret_cast<const f32x4*>(bA1 + w*16 + q*4);
        float a0 = fmaxf(D[0]+ba[0], 0.f), a1v = fmaxf(D[1]+ba[1], 0.f);
        float a2v = fmaxf(D[2]+ba[2], 0.f), a3v = fmaxf(D[3]+ba[3], 0.f);
        *reinterpret_cast<float2*>(&aL[ss][w*16 + q*4])     = make_float2(a0, a1v);
        *reinterpret_cast<float2*>(&aL[ss][w*16 + q*4 + 2]) = make_float2(a2v, a3v);
    }
    __syncthreads();

    // Phase D: out = tanh(a @ W_a2^T + b_a2)
    if (tid < 64) {
        const int s = tid & 31, o = tid >> 5;
        const float* wr = wA2L + o*64;
        float p = 0.f;
        #pragma unroll
        for (int d = 0; d < 64; ++d) p = fmaf(aL[s][d], wr[d], p);
        outg[(size_t)(b0 + s)*2 + o] = tanhf(p + bA2[o]);
    }
}

extern "C" void kernel_launch(void* const* d_in, const int* in_sizes, int n_in,
                              void* d_out, int out_size, void* d_ws, size_t ws_size,
                              hipStream_t stream) {
    const float* s0   = (const float*)d_in[0];
    const float* s1   = (const float*)d_in[1];
    const float* s2   = (const float*)d_in[2];
    const float* wOwn = (const float*)d_in[3];
    const float* bOwn = (const float*)d_in[4];
    const float* wEnv = (const float*)d_in[5];
    const float* bEnv = (const float*)d_in[6];
    const float* wS1  = (const float*)d_in[7];
    const float* bS1  = (const float*)d_in[8];
    const float* wS2  = (const float*)d_in[9];
    const float* bS2  = (const float*)d_in[10];
    const float* wQ   = (const float*)d_in[11];
    const float* wK   = (const float*)d_in[12];
    const float* wV   = (const float*)d_in[13];
    // d_in[14] (W_cq) / d_in[15] (W_ck): dead code in the reference.
    const float* wCv  = (const float*)d_in[16];
    const float* wMo  = (const float*)d_in[17];
    const float* bMo  = (const float*)d_in[18];
    const float* wA1  = (const float*)d_in[19];
    const float* bA1  = (const float*)d_in[20];
    const float* wA2  = (const float*)d_in[21];
    const float* bA2  = (const float*)d_in[22];
    float*    ws  = (float*)d_ws;
    unsigned* xbu = (unsigned*)d_ws + WS_XBU;
    float*    out = (float*)d_out;

    hipLaunchKernelGGL(actor_setup, dim3(WS_WEND / 256), dim3(256), 0, stream,
                       wOwn, wEnv, wS1, wS2, wQ, wK, wCv, wMo, wA1, ws);
    hipLaunchKernelGGL(actor_pre, dim3(16384 / 32), dim3(256), 0, stream,
                       s0, s1, bOwn, bEnv, ws, xbu);
    hipLaunchKernelGGL(actor_neigh, dim3(16384 / (4 * EPW)), dim3(256), 0, stream,
                       s2, bS1, bS2, wV, ws, xbu);
    hipLaunchKernelGGL(actor_tail, dim3(16384 / 32), dim3(256), 0, stream,
                       bMo, bA1, wA2, bA2, ws, xbu, out);
}

// Round 5
// 63.096 us; speedup vs baseline: 5.0785x; 1.2934x over previous
//
#include <hip/hip_runtime.h>
#include <hip/hip_bf16.h>
#include <math.h>

// ---------------------------------------------------------------------------
// ActorNetwork, round 5: ILP-restructured neighbor kernel.
//
// Exact algebraic folds: W_cq/W_ck dead; score via wQK = W_q^T W_k;
// pool-then-project for W_v, now FOLDED INTO the mo weights:
//   mo contribution of v_att = P @ (W_fold[:,128:192] @ W_v)^T, so K2 emits
//   pooled P directly and v_att is never materialized.
//
// Round-5 changes (theory: K2 latency-bound, VALUBusy 26%, MfmaUtil 4.4%,
// serial per-element chain + 68 shfl butterfly):
//   * K2 columns = 4 elements x 4 neighbors: 8 independent iterations/wave,
//     butterfly cut to 2 DPP rounds per 4 elements (was 4 rounds/element).
//   * Bias as MFMA C-operand; __float22bfloat162_rn packing (v_cvt_pk).
//   * H LDS double-buffered by iteration parity; launch_bounds(256,3).
// ---------------------------------------------------------------------------

typedef __attribute__((ext_vector_type(8))) short short8;
typedef __attribute__((ext_vector_type(4))) float f32x4;

// ws layout (4-byte units)
#define WS_A1F   0        // [4 ht][256]   bf16 A-frags W_s1 (K=16 padded to 32)
#define WS_A2F   1024     // [8 f][256]    bf16 A-frags W_s2
#define WS_QK    3072     // [64][64] f32  W_q^T @ W_k
#define WS_FOLDF 7168     // [48 f][256]   bf16 A-frags W_fold (h2 block x W_v)
#define WS_A1FR  19456    // [16 f][256]   bf16 A-frags W_a1
#define WS_ENVT  23552    // [64][64] f32  W_env^T
#define WS_OWNT  27648    // [16][64] f32  W_own^T
#define WS_SETUP_END 28672
#define WS_WCVV  28672    // [64][64] f32  W_cv @ W_v
#define WS_WEND  32768
#define WS_XBU   32768    // [16384][128] uint = [16384][256] bf16 X rows:
                          //   [0:64 own | 64:128 env | 128:192 P | 192:256 qk]

static __device__ inline unsigned pk2(float a, float b) {
    union { __hip_bfloat162 h; unsigned u; } cv;
    cv.h = __float22bfloat162_rn(make_float2(a, b));
    return cv.u;
}
static __device__ inline float bflo(unsigned u) {
    union { unsigned x; float f; } c; c.x = u << 16; return c.f;
}
static __device__ inline float bfhi(unsigned u) {
    union { unsigned x; float f; } c; c.x = u & 0xffff0000u; return c.f;
}

// ------------------------------------------------------- K0a: WCVV = Wcv@Wv
__global__ void actor_wcvv(const float* __restrict__ wCv,
                           const float* __restrict__ wV,
                           float* __restrict__ ws)
{
    int t = blockIdx.x * 256 + threadIdx.x;   // t < 4096
    int c = t >> 6, d = t & 63;
    float acc = 0.f;
    for (int e = 0; e < 64; ++e) acc = fmaf(wCv[c * 64 + e], wV[e * 64 + d], acc);
    ws[WS_WCVV + t] = acc;
}

// ---------------------------------------------------------------- K0: setup
__global__ void actor_setup(
    const float* __restrict__ wOwn, const float* __restrict__ wEnv,
    const float* __restrict__ wS1,  const float* __restrict__ wS2,
    const float* __restrict__ wQ,   const float* __restrict__ wK,
    const float* __restrict__ wCv,  const float* __restrict__ wMo,
    const float* __restrict__ wA1,  float* __restrict__ ws)
{
    int t = blockIdx.x * 256 + threadIdx.x;
    unsigned* wsu = reinterpret_cast<unsigned*>(ws);
    if (t < 1024) {                        // A1F: A[m][k]=W_s1[ht*16+m][k], k<16 else 0
        int ht = t >> 8, rem = t & 255, lane = rem >> 2, jj = rem & 3;
        int q = lane >> 4, m = lane & 15;
        int row = ht * 16 + m, k0 = q * 8 + jj * 2;
        float v0 = (k0 < 16) ? wS1[row * 16 + k0]     : 0.f;
        float v1 = (k0 < 16) ? wS1[row * 16 + k0 + 1] : 0.f;
        wsu[WS_A1F + t] = pk2(v0, v1);
    } else if (t < 3072) {                 // A2F: A[m][k]=W_s2[dt*16+m][kt*32+k]
        int u = t - 1024;
        int f = u >> 8, rem = u & 255, lane = rem >> 2, jj = rem & 3;
        int q = lane >> 4, m = lane & 15;
        int dt = f >> 1, kt = f & 1;
        int row = dt * 16 + m, k = kt * 32 + q * 8 + jj * 2;
        wsu[WS_A2F + u] = pk2(wS2[row * 64 + k], wS2[row * 64 + k + 1]);
    } else if (t < 7168) {                 // wQK[e][dp]
        int u = t - 3072; int e = u >> 6, dp = u & 63;
        float acc = 0.f;
        for (int d = 0; d < 64; ++d) acc += wQ[d * 64 + e] * wK[d * 64 + dp];
        ws[WS_QK + u] = acc;
    } else if (t < 19456) {                // FOLDF frags (h=2 block folded w/ W_v)
        int u = t - 7168;
        int f = u >> 8, rem = u & 255, lane = rem >> 2, jj = rem & 3;
        int RT = f / 6, kt = f - RT * 6;
        int row = RT * 16 + (lane & 15);
        int k = kt * 32 + (lane >> 4) * 8 + jj * 2;
        int h = k >> 6, dp = k & 63;
        const float* wmr = wMo + row * 192 + h * 64;
        const float* rhs = (h == 2) ? (ws + WS_WCVV) : wCv;   // WCVV = Wcv@Wv
        float a0 = 0.f, a1 = 0.f;
        for (int d = 0; d < 64; ++d) {
            float m = wmr[d];
            a0 = fmaf(m, rhs[d * 64 + dp],     a0);
            a1 = fmaf(m, rhs[d * 64 + dp + 1], a1);
        }
        wsu[WS_FOLDF + u] = pk2(a0, a1);
    } else if (t < 23552) {                // A1FR: W_a1 frags
        int u = t - 19456;
        int f = u >> 8, rem = u & 255, lane = rem >> 2, jj = rem & 3;
        int rt = f >> 2, kt = f & 3;
        int row = rt * 16 + (lane & 15);
        int k = kt * 32 + (lane >> 4) * 8 + jj * 2;
        wsu[WS_A1FR + u] = pk2(wA1[row * 128 + k], wA1[row * 128 + k + 1]);
    } else if (t < 27648) {                // wEnvT[k][d]
        int u = t - 23552; int k = u >> 6, d = u & 63;
        ws[WS_ENVT + u] = wEnv[d * 64 + k];
    } else if (t < WS_SETUP_END) {         // wOwnT[k][d]
        int u = t - 27648; int k = u >> 6, d = u & 63;
        ws[WS_OWNT + u] = wOwn[d * 16 + k];
    }
}

// ----------------------------------------------- K1: own_e, env_e, qk -> X
__global__ __launch_bounds__(256) void actor_pre(
    const float* __restrict__ s0g, const float* __restrict__ s1g,
    const float* __restrict__ bOwn, const float* __restrict__ bEnv,
    const float* __restrict__ ws,   unsigned* __restrict__ xbu)
{
    const float* __restrict__ wOwnT = ws + WS_OWNT;
    const float* __restrict__ wQK   = ws + WS_QK;
    const float* __restrict__ wEnvT = ws + WS_ENVT;
    __shared__ float ownL[32][68];
    const int tid = threadIdx.x;
    const int el = tid >> 3, g = tid & 7;
    const int b = blockIdx.x * 32 + el;
    unsigned* xrow = xbu + (size_t)b * 128;

    // own_e
    float s0r[16];
    {
        const float4* p = reinterpret_cast<const float4*>(s0g + (size_t)b * 16);
        #pragma unroll
        for (int qq = 0; qq < 4; ++qq) {
            float4 v = p[qq];
            s0r[qq*4+0]=v.x; s0r[qq*4+1]=v.y; s0r[qq*4+2]=v.z; s0r[qq*4+3]=v.w;
        }
    }
    {
        float4 b0 = *reinterpret_cast<const float4*>(bOwn + g*8);
        float4 b1 = *reinterpret_cast<const float4*>(bOwn + g*8 + 4);
        float ow[8] = {b0.x,b0.y,b0.z,b0.w,b1.x,b1.y,b1.z,b1.w};
        #pragma unroll
        for (int k = 0; k < 16; ++k) {
            float sk = s0r[k];
            const float* wr = wOwnT + k*64 + g*8;
            float4 w0 = *reinterpret_cast<const float4*>(wr);
            float4 w1 = *reinterpret_cast<const float4*>(wr + 4);
            ow[0]=fmaf(sk,w0.x,ow[0]); ow[1]=fmaf(sk,w0.y,ow[1]);
            ow[2]=fmaf(sk,w0.z,ow[2]); ow[3]=fmaf(sk,w0.w,ow[3]);
            ow[4]=fmaf(sk,w1.x,ow[4]); ow[5]=fmaf(sk,w1.y,ow[5]);
            ow[6]=fmaf(sk,w1.z,ow[6]); ow[7]=fmaf(sk,w1.w,ow[7]);
        }
        #pragma unroll
        for (int jj = 0; jj < 8; ++jj) ow[jj] = fmaxf(ow[jj], 0.f);
        *reinterpret_cast<float4*>(&ownL[el][g*8])     = make_float4(ow[0],ow[1],ow[2],ow[3]);
        *reinterpret_cast<float4*>(&ownL[el][g*8 + 4]) = make_float4(ow[4],ow[5],ow[6],ow[7]);
        reinterpret_cast<uint4*>(xrow)[g] =
            make_uint4(pk2(ow[0],ow[1]), pk2(ow[2],ow[3]), pk2(ow[4],ow[5]), pk2(ow[6],ow[7]));
    }

    // qk = own_e @ wQK (same-wave RAW on ownL; no barrier)
    {
        float qs[8] = {0,0,0,0,0,0,0,0};
        #pragma unroll 2
        for (int e4 = 0; e4 < 16; ++e4) {
            float4 c4 = *reinterpret_cast<const float4*>(&ownL[el][e4*4]);
            #pragma unroll
            for (int qq = 0; qq < 4; ++qq) {
                float oe = (qq==0)?c4.x:(qq==1)?c4.y:(qq==2)?c4.z:c4.w;
                const float* wr = wQK + (e4*4+qq)*64 + g*8;
                float4 w0 = *reinterpret_cast<const float4*>(wr);
                float4 w1 = *reinterpret_cast<const float4*>(wr + 4);
                qs[0]=fmaf(oe,w0.x,qs[0]); qs[1]=fmaf(oe,w0.y,qs[1]);
                qs[2]=fmaf(oe,w0.z,qs[2]); qs[3]=fmaf(oe,w0.w,qs[3]);
                qs[4]=fmaf(oe,w1.x,qs[4]); qs[5]=fmaf(oe,w1.y,qs[5]);
                qs[6]=fmaf(oe,w1.z,qs[6]); qs[7]=fmaf(oe,w1.w,qs[7]);
            }
        }
        reinterpret_cast<uint4*>(xrow + 96)[g] =
            make_uint4(pk2(qs[0],qs[1]), pk2(qs[2],qs[3]), pk2(qs[4],qs[5]), pk2(qs[6],qs[7]));
    }

    // env_e
    {
        float4 b0 = *reinterpret_cast<const float4*>(bEnv + g*8);
        float4 b1 = *reinterpret_cast<const float4*>(bEnv + g*8 + 4);
        float ev[8] = {b0.x,b0.y,b0.z,b0.w,b1.x,b1.y,b1.z,b1.w};
        const float* s1b = s1g + (size_t)b * 64;
        #pragma unroll 2
        for (int k4 = 0; k4 < 16; ++k4) {
            float4 sv = *reinterpret_cast<const float4*>(s1b + k4*4);
            #pragma unroll
            for (int qq = 0; qq < 4; ++qq) {
                float sk = (qq==0)?sv.x:(qq==1)?sv.y:(qq==2)?sv.z:sv.w;
                const float* wr = wEnvT + (k4*4+qq)*64 + g*8;
                float4 w0 = *reinterpret_cast<const float4*>(wr);
                float4 w1 = *reinterpret_cast<const float4*>(wr + 4);
                ev[0]=fmaf(sk,w0.x,ev[0]); ev[1]=fmaf(sk,w0.y,ev[1]);
                ev[2]=fmaf(sk,w0.z,ev[2]); ev[3]=fmaf(sk,w0.w,ev[3]);
                ev[4]=fmaf(sk,w1.x,ev[4]); ev[5]=fmaf(sk,w1.y,ev[5]);
                ev[6]=fmaf(sk,w1.z,ev[6]); ev[7]=fmaf(sk,w1.w,ev[7]);
            }
        }
        #pragma unroll
        for (int jj = 0; jj < 8; ++jj) ev[jj] = fmaxf(ev[jj], 0.f);
        reinterpret_cast<uint4*>(xrow + 32)[g] =
            make_uint4(pk2(ev[0],ev[1]), pk2(ev[2],ev[3]), pk2(ev[4],ev[5]), pk2(ev[6],ev[7]));
    }
}

// ------------------------------------------------------- K2: MFMA neighbors
// Columns = 4 elements x 4 neighbor-slots; 8 iterations cover 32 neighbors.
__global__ __launch_bounds__(256, 3) void actor_neigh(
    const float* __restrict__ s2g, const float* __restrict__ bS1g,
    const float* __restrict__ bS2g, const float* __restrict__ ws,
    unsigned* __restrict__ xbu)
{
    const int lane = threadIdx.x & 63;
    const int wid  = threadIdx.x >> 6;
    const int q    = lane >> 4;
    const int r    = lane & 15;
    const int el   = r >> 2;        // local element 0..3
    const int j    = r & 3;         // neighbor sub-column 0..3

    __shared__ ushort Hl[4][2][16 * 72];   // [wave][parity][col][feat], pad 72

    short8 A1[4], A2[8];
    {
        const short8* p1 = reinterpret_cast<const short8*>(ws + WS_A1F);
        #pragma unroll
        for (int ht = 0; ht < 4; ++ht) A1[ht] = p1[ht * 64 + lane];
        const short8* p2 = reinterpret_cast<const short8*>(ws + WS_A2F);
        #pragma unroll
        for (int f = 0; f < 8; ++f) A2[f] = p2[f * 64 + lane];
    }
    // biases as MFMA C-init fragments
    f32x4 b1c[4], b2c[4];
    #pragma unroll
    for (int t4 = 0; t4 < 4; ++t4) {
        b1c[t4] = *reinterpret_cast<const f32x4*>(bS1g + t4 * 16 + q * 4);
        b2c[t4] = *reinterpret_cast<const f32x4*>(bS2g + t4 * 16 + q * 4);
    }

    const int be = blockIdx.x * 16 + wid * 4 + el;   // this lane's element

    // qk[be][dt*16+q*4+i] (bf16 -> f32, 16 regs)
    float qkf[16];
    {
        const unsigned* qrow = xbu + (size_t)be * 128 + 96;
        #pragma unroll
        for (int dt = 0; dt < 4; ++dt) {
            uint2 u = *reinterpret_cast<const uint2*>(qrow + dt*8 + q*2);
            qkf[dt*4+0] = bflo(u.x); qkf[dt*4+1] = bfhi(u.x);
            qkf[dt*4+2] = bflo(u.y); qkf[dt*4+3] = bfhi(u.y);
        }
    }

    const float* s2base = s2g + (size_t)be * 512 + (q & 1) * 8;

    float den = 0.f;
    f32x4 Pac[4] = {{0,0,0,0},{0,0,0,0},{0,0,0,0},{0,0,0,0}};

    #pragma unroll 2
    for (int it = 0; it < 8; ++it) {
        // this lane's column: element `el`, neighbor it*4+j
        const float* sp = s2base + (it*4 + j) * 16;
        float4 sa = *reinterpret_cast<const float4*>(sp);
        float4 sb = *reinterpret_cast<const float4*>(sp + 4);
        union { short8 s8; unsigned u[4]; } B1;
        B1.u[0] = pk2(sa.x, sa.y); B1.u[1] = pk2(sa.z, sa.w);
        B1.u[2] = pk2(sb.x, sb.y); B1.u[3] = pk2(sb.z, sb.w);

        // GEMM1: H = relu(W_s1 @ S2^T + b1)
        f32x4 hD[4];
        #pragma unroll
        for (int ht = 0; ht < 4; ++ht)
            hD[ht] = __builtin_amdgcn_mfma_f32_16x16x32_bf16(A1[ht], B1.s8, b1c[ht], 0, 0, 0);

        ushort* hrow = &Hl[wid][it & 1][r * 72];
        #pragma unroll
        for (int ht = 0; ht < 4; ++ht) {
            float h0 = fmaxf(hD[ht][0], 0.f), h1 = fmaxf(hD[ht][1], 0.f);
            float h2 = fmaxf(hD[ht][2], 0.f), h3 = fmaxf(hD[ht][3], 0.f);
            *reinterpret_cast<uint2*>(hrow + ht*16 + q*4) =
                make_uint2(pk2(h0, h1), pk2(h2, h3));
        }
        short8 B2a = *reinterpret_cast<const short8*>(hrow + q * 8);
        short8 B2b = *reinterpret_cast<const short8*>(hrow + 32 + q * 8);

        // GEMM2: intru = relu(W_s2 @ H + b2)
        f32x4 iD[4];
        #pragma unroll
        for (int dt = 0; dt < 4; ++dt) {
            f32x4 c0 = __builtin_amdgcn_mfma_f32_16x16x32_bf16(A2[dt*2+0], B2a, b2c[dt], 0, 0, 0);
            iD[dt]   = __builtin_amdgcn_mfma_f32_16x16x32_bf16(A2[dt*2+1], B2b, c0, 0, 0, 0);
        }
        float rs = 0.f, sc = 0.f;
        #pragma unroll
        for (int dt = 0; dt < 4; ++dt) {
            #pragma unroll
            for (int i = 0; i < 4; ++i) {
                float x = fmaxf(iD[dt][i], 0.f);
                iD[dt][i] = x;
                rs += x;
                sc = fmaf(x, qkf[dt*4+i], sc);
            }
        }
        // reduce over features (q bits): all lanes get their column's sc/rs
        sc += __shfl_xor(sc, 16, 64);
        sc += __shfl_xor(sc, 32, 64);
        rs += __shfl_xor(rs, 16, 64);
        rs += __shfl_xor(rs, 32, 64);
        float w = (rs != 0.f) ? __expf(sc * 0.125f) : 0.f;  // scores O(1e-2)
        den += w;
        #pragma unroll
        for (int dt = 0; dt < 4; ++dt)
            #pragma unroll
            for (int i = 0; i < 4; ++i)
                Pac[dt][i] = fmaf(w, iD[dt][i], Pac[dt][i]);
    }

    // combine the 4 neighbor-columns of each element (lane bits 0,1 -> DPP)
    #pragma unroll
    for (int m = 1; m <= 2; m <<= 1) {
        den += __shfl_xor(den, m, 64);
        #pragma unroll
        for (int dt = 0; dt < 4; ++dt)
            #pragma unroll
            for (int i = 0; i < 4; ++i)
                Pac[dt][i] += __shfl_xor(Pac[dt][i], m, 64);
    }
    float inv = (den > 0.f) ? (1.f / den) : 0.f;   // all-masked -> P = 0
    if (j == 0) {
        unsigned* prow = xbu + (size_t)be * 128 + 64;
        #pragma unroll
        for (int dt = 0; dt < 4; ++dt) {
            float p0 = Pac[dt][0] * inv, p1 = Pac[dt][1] * inv;
            float p2 = Pac[dt][2] * inv, p3 = Pac[dt][3] * inv;
            *reinterpret_cast<uint2*>(prow + dt*8 + q*2) =
                make_uint2(pk2(p0, p1), pk2(p2, p3));
        }
    }
}

// ------------------------------------------------ K3: MFMA tail (mo,a1,a2)
__global__ __launch_bounds__(256) void actor_tail(
    const float* __restrict__ bMo, const float* __restrict__ bA1,
    const float* __restrict__ wA2, const float* __restrict__ bA2,
    const float* __restrict__ ws,  const unsigned* __restrict__ xbu,
    float* __restrict__ outg)
{
    const unsigned* wsu = reinterpret_cast<const unsigned*>(ws);
    __shared__ char  xbL[32 * 512];   // X rows, bf16, XOR-swizzled
    __shared__ char  mbL[32 * 256];   // mo rows, bf16, XOR-swizzled
    __shared__ float aL[32][66];      // a rows, fp32
    __shared__ float wA2L[128];

    const int tid  = threadIdx.x;
    const int w    = tid >> 6;
    const int lane = tid & 63;
    const int q    = lane >> 4;
    const int sl   = lane & 15;
    const int swz  = (sl & 7) << 4;
    const int b0   = blockIdx.x * 32;

    short8 Amo[2][6], Aa1[4];
    {
        const short8* fp = reinterpret_cast<const short8*>(wsu + WS_FOLDF);
        #pragma unroll
        for (int rt = 0; rt < 2; ++rt)
            #pragma unroll
            for (int kt = 0; kt < 6; ++kt)
                Amo[rt][kt] = fp[((w*2 + rt)*6 + kt)*64 + lane];
        const short8* ap = reinterpret_cast<const short8*>(wsu + WS_A1FR);
        #pragma unroll
        for (int kt = 0; kt < 4; ++kt)
            Aa1[kt] = ap[(w*4 + kt)*64 + lane];
    }

    // Phase A: stage X[0:192] bf16 into swizzled XB
    {
        const int s = tid & 31, jj = tid >> 5;   // jj 0..7
        const uint4* xrow = reinterpret_cast<const uint4*>(xbu + (size_t)(b0 + s) * 128);
        #pragma unroll
        for (int i = 0; i < 3; ++i) {
            int c = jj*3 + i;                    // 16B chunk 0..23
            uint4 v = xrow[c];
            *reinterpret_cast<uint4*>(xbL + s*512 + ((c*16) ^ ((s & 7) << 4))) = v;
        }
        if (tid < 32)
            reinterpret_cast<float4*>(wA2L)[tid] =
                reinterpret_cast<const float4*>(wA2)[tid];
    }
    __syncthreads();

    const f32x4 z = {0.f, 0.f, 0.f, 0.f};

    // Phase B: mo = X @ W_fold^T + b_mo -> MB (bf16)
    #pragma unroll
    for (int st = 0; st < 2; ++st) {
        const int ss = st*16 + sl;
        short8 Bf[6];
        #pragma unroll
        for (int kt = 0; kt < 6; ++kt)
            Bf[kt] = *reinterpret_cast<const short8*>(
                xbL + ss*512 + ((kt*64 + q*16) ^ swz));
        #pragma unroll
        for (int rt = 0; rt < 2; ++rt) {
            f32x4 D = z;
            #pragma unroll
            for (int kt = 0; kt < 6; ++kt)
                D = __builtin_amdgcn_mfma_f32_16x16x32_bf16(Amo[rt][kt], Bf[kt], D, 0, 0, 0);
            f32x4 bm = *reinterpret_cast<const f32x4*>(bMo + w*32 + rt*16 + q*4);
            char* wp = mbL + ss*256 + ((w*64 + rt*32 + q*8) ^ swz);
            *reinterpret_cast<unsigned*>(wp)     = pk2(D[0]+bm[0], D[1]+bm[1]);
            *reinterpret_cast<unsigned*>(wp + 4) = pk2(D[2]+bm[2], D[3]+bm[3]);
        }
    }
    __syncthreads();

    // Phase C: a = relu(mo @ W_a1^T + b_a1) -> aL (fp32)
    #pragma unroll
    for (int st = 0; st < 2; ++st) {
        const int ss = st*16 + sl;
        f32x4 D = z;
        #pragma unroll
        for (int kt = 0; kt < 4; ++kt) {
            short8 Bk = *reinterpret_cast<const short8*>(
                mbL + ss*256 + ((kt*64 + q*16) ^ swz));
            D = __builtin_amdgcn_mfma_f32_16x16x32_bf16(Aa1[kt], Bk, D, 0, 0, 0);
        }
        f32x4 ba = *reinterpret_cast<const f32x4*>(bA1 + w*16 + q*4);
        float a0 = fmaxf(D[0]+ba[0], 0.f), a1v = fmaxf(D[1]+ba[1], 0.f);
        float a2v = fmaxf(D[2]+ba[2], 0.f), a3v = fmaxf(D[3]+ba[3], 0.f);
        *reinterpret_cast<float2*>(&aL[ss][w*16 + q*4])     = make_float2(a0, a1v);
        *reinterpret_cast<float2*>(&aL[ss][w*16 + q*4 + 2]) = make_float2(a2v, a3v);
    }
    __syncthreads();

    // Phase D: out = tanh(a @ W_a2^T + b_a2)
    if (tid < 64) {
        const int s = tid & 31, o = tid >> 5;
        const float* wr = wA2L + o*64;
        float p = 0.f;
        #pragma unroll
        for (int d = 0; d < 64; ++d) p = fmaf(aL[s][d], wr[d], p);
        outg[(size_t)(b0 + s)*2 + o] = tanhf(p + bA2[o]);
    }
}

extern "C" void kernel_launch(void* const* d_in, const int* in_sizes, int n_in,
                              void* d_out, int out_size, void* d_ws, size_t ws_size,
                              hipStream_t stream) {
    const float* s0   = (const float*)d_in[0];
    const float* s1   = (const float*)d_in[1];
    const float* s2   = (const float*)d_in[2];
    const float* wOwn = (const float*)d_in[3];
    const float* bOwn = (const float*)d_in[4];
    const float* wEnv = (const float*)d_in[5];
    const float* bEnv = (const float*)d_in[6];
    const float* wS1  = (const float*)d_in[7];
    const float* bS1  = (const float*)d_in[8];
    const float* wS2  = (const float*)d_in[9];
    const float* bS2  = (const float*)d_in[10];
    const float* wQ   = (const float*)d_in[11];
    const float* wK   = (const float*)d_in[12];
    const float* wV   = (const float*)d_in[13];
    // d_in[14] (W_cq) / d_in[15] (W_ck): dead code in the reference.
    const float* wCv  = (const float*)d_in[16];
    const float* wMo  = (const float*)d_in[17];
    const float* bMo  = (const float*)d_in[18];
    const float* wA1  = (const float*)d_in[19];
    const float* bA1  = (const float*)d_in[20];
    const float* wA2  = (const float*)d_in[21];
    const float* bA2  = (const float*)d_in[22];
    float*    ws  = (float*)d_ws;
    unsigned* xbu = (unsigned*)d_ws + WS_XBU;
    float*    out = (float*)d_out;

    hipLaunchKernelGGL(actor_wcvv, dim3(16), dim3(256), 0, stream, wCv, wV, ws);
    hipLaunchKernelGGL(actor_setup, dim3(WS_SETUP_END / 256), dim3(256), 0, stream,
                       wOwn, wEnv, wS1, wS2, wQ, wK, wCv, wMo, wA1, ws);
    hipLaunchKernelGGL(actor_pre, dim3(16384 / 32), dim3(256), 0, stream,
                       s0, s1, bOwn, bEnv, ws, xbu);
    hipLaunchKernelGGL(actor_neigh, dim3(16384 / 16), dim3(256), 0, stream,
                       s2, bS1, bS2, ws, xbu);
    hipLaunchKernelGGL(actor_tail, dim3(16384 / 32), dim3(256), 0, stream,
                       bMo, bA1, wA2, bA2, ws, xbu, out);
}

// Round 6
// 40.255 us; speedup vs baseline: 7.9600x; 1.5674x over previous
//
#include <hip/hip_runtime.h>
#include <hip/hip_bf16.h>
#include <math.h>

// ---------------------------------------------------------------------------
// ActorNetwork, round 6: single fused MFMA kernel (16 elements / block).
//
// Exact algebraic folds: W_cq/W_ck dead; score via wQK = W_q^T W_k (bf16
// A-frags of wQK^T, computed directly from wQ/wK in setup); W_v folded into
// the mo weights via WCVV = W_cv @ W_v; W_fold = blockdiag fold of W_mo,W_cv.
//
// Round-6 changes (theory: r5 remaining cost = fp32-VALU actor_pre (~13us),
// X global round-trips, 5-launch overhead; MFMA floor is ~3us):
//   * One mega kernel: phase1 own/env/qk on MFMA (pre eliminated), phase2
//     neighbor loop (r5 structure), phase3 tail MFMA — all intermediates in
//     LDS (X tile 384B rows, XOR-swizzled; qk fp32 tile; H double-buffer).
//   * 3 launches total (wcvv, setup, mega); no X buffer in global at all.
// ---------------------------------------------------------------------------

typedef __attribute__((ext_vector_type(8))) short short8;
typedef __attribute__((ext_vector_type(4))) float f32x4;

// ws layout (4-byte units)
#define WS_A1F   0        // [4][256]  bf16 A-frags W_s1 (K=16 padded to 32)
#define WS_A2F   1024     // [8][256]  bf16 A-frags W_s2
#define WS_AOWN  3072     // [4][256]  bf16 A-frags W_own (K=16 padded to 32)
#define WS_AENV  4096     // [8][256]  bf16 A-frags W_env
#define WS_AQK   6144     // [8][256]  bf16 A-frags wQK^T (= (W_q^T W_k)^T)
#define WS_FOLDF 8192     // [48][256] bf16 A-frags W_fold (h2 block x W_v)
#define WS_A1FR  20480    // [16][256] bf16 A-frags W_a1
#define WS_SETUP_END 24576
#define WS_WCVV  24576    // [64][64] f32  W_cv @ W_v
#define WS_WEND  28672

static __device__ inline unsigned pk2(float a, float b) {
    union { __hip_bfloat162 h; unsigned u; } cv;
    cv.h = __float22bfloat162_rn(make_float2(a, b));
    return cv.u;
}

// ------------------------------------------------------- K0a: WCVV = Wcv@Wv
__global__ void actor_wcvv(const float* __restrict__ wCv,
                           const float* __restrict__ wV,
                           float* __restrict__ ws)
{
    int t = blockIdx.x * 256 + threadIdx.x;   // t < 4096
    int c = t >> 6, d = t & 63;
    float acc = 0.f;
    for (int e = 0; e < 64; ++e) acc = fmaf(wCv[c * 64 + e], wV[e * 64 + d], acc);
    ws[WS_WCVV + t] = acc;
}

// ---------------------------------------------------------------- K0: setup
__global__ void actor_setup(
    const float* __restrict__ wOwn, const float* __restrict__ wEnv,
    const float* __restrict__ wS1,  const float* __restrict__ wS2,
    const float* __restrict__ wQ,   const float* __restrict__ wK,
    const float* __restrict__ wCv,  const float* __restrict__ wMo,
    const float* __restrict__ wA1,  float* __restrict__ ws)
{
    int t = blockIdx.x * 256 + threadIdx.x;
    unsigned* wsu = reinterpret_cast<unsigned*>(ws);
    if (t < 1024) {                        // A1F: A[m][k]=W_s1[ht*16+m][k], k<16 else 0
        int ht = t >> 8, rem = t & 255, lane = rem >> 2, jj = rem & 3;
        int qq = lane >> 4, m = lane & 15;
        int row = ht * 16 + m, k0 = qq * 8 + jj * 2;
        float v0 = (k0 < 16) ? wS1[row * 16 + k0]     : 0.f;
        float v1 = (k0 < 16) ? wS1[row * 16 + k0 + 1] : 0.f;
        wsu[WS_A1F + t] = pk2(v0, v1);
    } else if (t < 3072) {                 // A2F: A[m][k]=W_s2[dt*16+m][kt*32+k]
        int u = t - 1024;
        int f = u >> 8, rem = u & 255, lane = rem >> 2, jj = rem & 3;
        int qq = lane >> 4, m = lane & 15;
        int dt = f >> 1, kt = f & 1;
        int row = dt * 16 + m, k = kt * 32 + qq * 8 + jj * 2;
        wsu[WS_A2F + u] = pk2(wS2[row * 64 + k], wS2[row * 64 + k + 1]);
    } else if (t < 4096) {                 // AOWN: A[m][k]=W_own[ht*16+m][k], k<16 else 0
        int u = t - 3072;
        int ht = u >> 8, rem = u & 255, lane = rem >> 2, jj = rem & 3;
        int qq = lane >> 4, m = lane & 15;
        int row = ht * 16 + m, k0 = qq * 8 + jj * 2;
        float v0 = (k0 < 16) ? wOwn[row * 16 + k0]     : 0.f;
        float v1 = (k0 < 16) ? wOwn[row * 16 + k0 + 1] : 0.f;
        wsu[WS_AOWN + u] = pk2(v0, v1);
    } else if (t < 6144) {                 // AENV: A[m][k]=W_env[ht*16+m][kt*32+k]
        int u = t - 4096;
        int f = u >> 8, rem = u & 255, lane = rem >> 2, jj = rem & 3;
        int qq = lane >> 4, m = lane & 15;
        int ht = f >> 1, kt = f & 1;
        int row = ht * 16 + m, k = kt * 32 + qq * 8 + jj * 2;
        wsu[WS_AENV + u] = pk2(wEnv[row * 64 + k], wEnv[row * 64 + k + 1]);
    } else if (t < 8192) {                 // AQK: A[m=dp][k=e] = wQK[e][dp] = sum_d wQ[d][e] wK[d][dp]
        int u = t - 6144;
        int f = u >> 8, rem = u & 255, lane = rem >> 2, jj = rem & 3;
        int qq = lane >> 4, m = lane & 15;
        int dt = f >> 1, kt = f & 1;
        int dp = dt * 16 + m;
        int e = kt * 32 + qq * 8 + jj * 2;
        float a0 = 0.f, a1 = 0.f;
        for (int d = 0; d < 64; ++d) {
            float kd = wK[d * 64 + dp];
            a0 = fmaf(wQ[d * 64 + e],     kd, a0);
            a1 = fmaf(wQ[d * 64 + e + 1], kd, a1);
        }
        wsu[WS_AQK + u] = pk2(a0, a1);
    } else if (t < 20480) {                // FOLDF frags (h=2 block folded w/ W_v)
        int u = t - 8192;
        int f = u >> 8, rem = u & 255, lane = rem >> 2, jj = rem & 3;
        int RT = f / 6, kt = f - RT * 6;
        int row = RT * 16 + (lane & 15);
        int k = kt * 32 + (lane >> 4) * 8 + jj * 2;
        int h = k >> 6, dp = k & 63;
        const float* wmr = wMo + row * 192 + h * 64;
        const float* rhs = (h == 2) ? (ws + WS_WCVV) : wCv;   // WCVV = Wcv@Wv
        float a0 = 0.f, a1 = 0.f;
        for (int d = 0; d < 64; ++d) {
            float m = wmr[d];
            a0 = fmaf(m, rhs[d * 64 + dp],     a0);
            a1 = fmaf(m, rhs[d * 64 + dp + 1], a1);
        }
        wsu[WS_FOLDF + u] = pk2(a0, a1);
    } else if (t < WS_SETUP_END) {         // A1FR: W_a1 frags
        int u = t - 20480;
        int f = u >> 8, rem = u & 255, lane = rem >> 2, jj = rem & 3;
        int rt = f >> 2, kt = f & 3;
        int row = rt * 16 + (lane & 15);
        int k = kt * 32 + (lane >> 4) * 8 + jj * 2;
        wsu[WS_A1FR + u] = pk2(wA1[row * 128 + k], wA1[row * 128 + k + 1]);
    }
}

// -------------------------------------------------------- K1: fused pipeline
__global__ __launch_bounds__(256, 3) void actor_mega(
    const float* __restrict__ s0g, const float* __restrict__ s1g,
    const float* __restrict__ s2g,
    const float* __restrict__ bOwn, const float* __restrict__ bEnv,
    const float* __restrict__ bS1g, const float* __restrict__ bS2g,
    const float* __restrict__ bMo,  const float* __restrict__ bA1,
    const float* __restrict__ wA2,  const float* __restrict__ bA2,
    const float* __restrict__ ws,   float* __restrict__ outg)
{
    // X tile: 16 rows x 384B (192 bf16: [0:64 own | 64:128 env | 128:192 P]),
    // XOR-swizzled by (row&7)<<4.
    __shared__ char   xbL[16 * 384];
    __shared__ float  qkL[16][72];          // fp32 qk rows (stride 72: 16B-aligned cols)
    __shared__ ushort Hl[4][2][16 * 72];    // per-wave H double-buffer
    __shared__ ushort TR[16 * 72];          // own_e^T staging for qk B-frag
    __shared__ char   mbL[16 * 256];        // mo rows bf16, swizzled
    __shared__ float  aL[16][66];           // a rows fp32

    const int tid  = threadIdx.x;
    const int wid  = tid >> 6;
    const int lane = tid & 63;
    const int q    = lane >> 4;
    const int r    = lane & 15;
    const int swzr = (r & 7) << 4;
    const int eb   = blockIdx.x * 16;
    const f32x4 z = {0.f, 0.f, 0.f, 0.f};

    // ---------------- Phase 1a: own_e (wave wid -> feature tile ht=wid)
    {
        short8 Ao = reinterpret_cast<const short8*>(ws + WS_AOWN)[wid * 64 + lane];
        const float* sp = s0g + (size_t)(eb + r) * 16 + (q & 1) * 8;
        float4 sa = *reinterpret_cast<const float4*>(sp);
        float4 sb = *reinterpret_cast<const float4*>(sp + 4);
        union { short8 s8; unsigned u[4]; } B;
        B.u[0] = pk2(sa.x, sa.y); B.u[1] = pk2(sa.z, sa.w);
        B.u[2] = pk2(sb.x, sb.y); B.u[3] = pk2(sb.z, sb.w);
        f32x4 c = *reinterpret_cast<const f32x4*>(bOwn + wid * 16 + q * 4);
        f32x4 D = __builtin_amdgcn_mfma_f32_16x16x32_bf16(Ao, B.s8, c, 0, 0, 0);
        unsigned p0 = pk2(fmaxf(D[0], 0.f), fmaxf(D[1], 0.f));
        unsigned p1 = pk2(fmaxf(D[2], 0.f), fmaxf(D[3], 0.f));
        *reinterpret_cast<uint2*>(xbL + r * 384 + ((wid * 32 + q * 8) ^ swzr)) =
            make_uint2(p0, p1);
        *reinterpret_cast<uint2*>(reinterpret_cast<char*>(TR) + r * 144 + wid * 32 + q * 8) =
            make_uint2(p0, p1);
    }
    // ---------------- Phase 1b: env_e
    {
        short8 Ae0 = reinterpret_cast<const short8*>(ws + WS_AENV)[(wid * 2 + 0) * 64 + lane];
        short8 Ae1 = reinterpret_cast<const short8*>(ws + WS_AENV)[(wid * 2 + 1) * 64 + lane];
        const float* sb1 = s1g + (size_t)(eb + r) * 64;
        f32x4 D = *reinterpret_cast<const f32x4*>(bEnv + wid * 16 + q * 4);
        {
            float4 sa = *reinterpret_cast<const float4*>(sb1 + q * 8);
            float4 sb = *reinterpret_cast<const float4*>(sb1 + q * 8 + 4);
            union { short8 s8; unsigned u[4]; } B;
            B.u[0] = pk2(sa.x, sa.y); B.u[1] = pk2(sa.z, sa.w);
            B.u[2] = pk2(sb.x, sb.y); B.u[3] = pk2(sb.z, sb.w);
            D = __builtin_amdgcn_mfma_f32_16x16x32_bf16(Ae0, B.s8, D, 0, 0, 0);
        }
        {
            float4 sa = *reinterpret_cast<const float4*>(sb1 + 32 + q * 8);
            float4 sb = *reinterpret_cast<const float4*>(sb1 + 32 + q * 8 + 4);
            union { short8 s8; unsigned u[4]; } B;
            B.u[0] = pk2(sa.x, sa.y); B.u[1] = pk2(sa.z, sa.w);
            B.u[2] = pk2(sb.x, sb.y); B.u[3] = pk2(sb.z, sb.w);
            D = __builtin_amdgcn_mfma_f32_16x16x32_bf16(Ae1, B.s8, D, 0, 0, 0);
        }
        unsigned p0 = pk2(fmaxf(D[0], 0.f), fmaxf(D[1], 0.f));
        unsigned p1 = pk2(fmaxf(D[2], 0.f), fmaxf(D[3], 0.f));
        *reinterpret_cast<uint2*>(xbL + r * 384 + ((128 + wid * 32 + q * 8) ^ swzr)) =
            make_uint2(p0, p1);
    }
    __syncthreads();   // TR complete (all waves' feature tiles)

    // ---------------- Phase 1c: qk = own_e @ wQK (wave wid -> dp tile wid)
    {
        short8 Aq0 = reinterpret_cast<const short8*>(ws + WS_AQK)[(wid * 2 + 0) * 64 + lane];
        short8 Aq1 = reinterpret_cast<const short8*>(ws + WS_AQK)[(wid * 2 + 1) * 64 + lane];
        const char* trb = reinterpret_cast<const char*>(TR) + r * 144;
        short8 B0 = *reinterpret_cast<const short8*>(trb + q * 16);
        short8 B1 = *reinterpret_cast<const short8*>(trb + 64 + q * 16);
        f32x4 D = __builtin_amdgcn_mfma_f32_16x16x32_bf16(Aq0, B0, z, 0, 0, 0);
        D = __builtin_amdgcn_mfma_f32_16x16x32_bf16(Aq1, B1, D, 0, 0, 0);
        *reinterpret_cast<f32x4*>(&qkL[r][wid * 16 + q * 4]) = D;
    }
    __syncthreads();   // qkL complete

    // ---------------- Phase 2: neighbor loop (4 elements x 4 neighbors / wave)
    short8 A1[4], A2[8];
    {
        const short8* p1 = reinterpret_cast<const short8*>(ws + WS_A1F);
        #pragma unroll
        for (int ht = 0; ht < 4; ++ht) A1[ht] = p1[ht * 64 + lane];
        const short8* p2 = reinterpret_cast<const short8*>(ws + WS_A2F);
        #pragma unroll
        for (int f = 0; f < 8; ++f) A2[f] = p2[f * 64 + lane];
    }
    f32x4 b1c[4], b2c[4];
    #pragma unroll
    for (int t4 = 0; t4 < 4; ++t4) {
        b1c[t4] = *reinterpret_cast<const f32x4*>(bS1g + t4 * 16 + q * 4);
        b2c[t4] = *reinterpret_cast<const f32x4*>(bS2g + t4 * 16 + q * 4);
    }
    const int el   = r >> 2;              // local element within wave
    const int j    = r & 3;               // neighbor sub-column
    const int sloc = wid * 4 + el;        // block-local sample 0..15

    float qkf[16];
    #pragma unroll
    for (int dt = 0; dt < 4; ++dt) {
        f32x4 v = *reinterpret_cast<const f32x4*>(&qkL[sloc][dt * 16 + q * 4]);
        qkf[dt*4+0] = v[0]; qkf[dt*4+1] = v[1]; qkf[dt*4+2] = v[2]; qkf[dt*4+3] = v[3];
    }
    const float* s2base = s2g + (size_t)(eb + sloc) * 512 + (q & 1) * 8;

    float den = 0.f;
    f32x4 Pac[4] = {{0,0,0,0},{0,0,0,0},{0,0,0,0},{0,0,0,0}};

    #pragma unroll 2
    for (int it = 0; it < 8; ++it) {
        const float* sp = s2base + (it * 4 + j) * 16;
        float4 sa = *reinterpret_cast<const float4*>(sp);
        float4 sb = *reinterpret_cast<const float4*>(sp + 4);
        union { short8 s8; unsigned u[4]; } B1;
        B1.u[0] = pk2(sa.x, sa.y); B1.u[1] = pk2(sa.z, sa.w);
        B1.u[2] = pk2(sb.x, sb.y); B1.u[3] = pk2(sb.z, sb.w);

        f32x4 hD[4];
        #pragma unroll
        for (int ht = 0; ht < 4; ++ht)
            hD[ht] = __builtin_amdgcn_mfma_f32_16x16x32_bf16(A1[ht], B1.s8, b1c[ht], 0, 0, 0);

        ushort* hrow = &Hl[wid][it & 1][r * 72];
        #pragma unroll
        for (int ht = 0; ht < 4; ++ht) {
            float h0 = fmaxf(hD[ht][0], 0.f), h1 = fmaxf(hD[ht][1], 0.f);
            float h2 = fmaxf(hD[ht][2], 0.f), h3 = fmaxf(hD[ht][3], 0.f);
            *reinterpret_cast<uint2*>(hrow + ht * 16 + q * 4) =
                make_uint2(pk2(h0, h1), pk2(h2, h3));
        }
        short8 B2a = *reinterpret_cast<const short8*>(hrow + q * 8);
        short8 B2b = *reinterpret_cast<const short8*>(hrow + 32 + q * 8);

        f32x4 iD[4];
        #pragma unroll
        for (int dt = 0; dt < 4; ++dt) {
            f32x4 c0 = __builtin_amdgcn_mfma_f32_16x16x32_bf16(A2[dt*2+0], B2a, b2c[dt], 0, 0, 0);
            iD[dt]   = __builtin_amdgcn_mfma_f32_16x16x32_bf16(A2[dt*2+1], B2b, c0, 0, 0, 0);
        }
        float rs = 0.f, sc = 0.f;
        #pragma unroll
        for (int dt = 0; dt < 4; ++dt) {
            #pragma unroll
            for (int i = 0; i < 4; ++i) {
                float x = fmaxf(iD[dt][i], 0.f);
                iD[dt][i] = x;
                rs += x;
                sc = fmaf(x, qkf[dt*4+i], sc);
            }
        }
        sc += __shfl_xor(sc, 16, 64);
        sc += __shfl_xor(sc, 32, 64);
        rs += __shfl_xor(rs, 16, 64);
        rs += __shfl_xor(rs, 32, 64);
        float w = (rs != 0.f) ? __expf(sc * 0.125f) : 0.f;  // scores O(1e-2)
        den += w;
        #pragma unroll
        for (int dt = 0; dt < 4; ++dt)
            #pragma unroll
            for (int i = 0; i < 4; ++i)
                Pac[dt][i] = fmaf(w, iD[dt][i], Pac[dt][i]);
    }
    #pragma unroll
    for (int m = 1; m <= 2; m <<= 1) {
        den += __shfl_xor(den, m, 64);
        #pragma unroll
        for (int dt = 0; dt < 4; ++dt)
            #pragma unroll
            for (int i = 0; i < 4; ++i)
                Pac[dt][i] += __shfl_xor(Pac[dt][i], m, 64);
    }
    {
        float inv = (den > 0.f) ? (1.f / den) : 0.f;   // all-masked -> P = 0
        if (j == 0) {
            const int swzs = (sloc & 7) << 4;
            #pragma unroll
            for (int dt = 0; dt < 4; ++dt) {
                float p0 = Pac[dt][0] * inv, p1 = Pac[dt][1] * inv;
                float p2 = Pac[dt][2] * inv, p3 = Pac[dt][3] * inv;
                *reinterpret_cast<uint2*>(xbL + sloc * 384 + ((256 + dt * 32 + q * 8) ^ swzs)) =
                    make_uint2(pk2(p0, p1), pk2(p2, p3));
            }
        }
    }
    __syncthreads();   // X tile complete

    // ---------------- Phase 3a: mo = X @ W_fold^T + b_mo
    {
        const short8* fp = reinterpret_cast<const short8*>(ws + WS_FOLDF);
        short8 Amo0[6], Amo1[6];
        #pragma unroll
        for (int kt = 0; kt < 6; ++kt) {
            Amo0[kt] = fp[((wid * 2 + 0) * 6 + kt) * 64 + lane];
            Amo1[kt] = fp[((wid * 2 + 1) * 6 + kt) * 64 + lane];
        }
        short8 Bf[6];
        #pragma unroll
        for (int kt = 0; kt < 6; ++kt)
            Bf[kt] = *reinterpret_cast<const short8*>(
                xbL + r * 384 + ((kt * 64 + q * 16) ^ swzr));
        f32x4 D0 = z, D1 = z;
        #pragma unroll
        for (int kt = 0; kt < 6; ++kt) {
            D0 = __builtin_amdgcn_mfma_f32_16x16x32_bf16(Amo0[kt], Bf[kt], D0, 0, 0, 0);
            D1 = __builtin_amdgcn_mfma_f32_16x16x32_bf16(Amo1[kt], Bf[kt], D1, 0, 0, 0);
        }
        f32x4 bm0 = *reinterpret_cast<const f32x4*>(bMo + wid * 32 + q * 4);
        f32x4 bm1 = *reinterpret_cast<const f32x4*>(bMo + wid * 32 + 16 + q * 4);
        char* wp0 = mbL + r * 256 + ((wid * 64 + q * 8) ^ swzr);
        *reinterpret_cast<unsigned*>(wp0)     = pk2(D0[0] + bm0[0], D0[1] + bm0[1]);
        *reinterpret_cast<unsigned*>(wp0 + 4) = pk2(D0[2] + bm0[2], D0[3] + bm0[3]);
        char* wp1 = mbL + r * 256 + ((wid * 64 + 32 + q * 8) ^ swzr);
        *reinterpret_cast<unsigned*>(wp1)     = pk2(D1[0] + bm1[0], D1[1] + bm1[1]);
        *reinterpret_cast<unsigned*>(wp1 + 4) = pk2(D1[2] + bm1[2], D1[3] + bm1[3]);
    }
    __syncthreads();   // mo tile complete

    // ---------------- Phase 3b: a = relu(mo @ W_a1^T + b_a1)
    {
        const short8* ap = reinterpret_cast<const short8*>(ws + WS_A1FR);
        f32x4 D = z;
        #pragma unroll
        for (int kt = 0; kt < 4; ++kt) {
            short8 Ak = ap[(wid * 4 + kt) * 64 + lane];
            short8 Bk = *reinterpret_cast<const short8*>(
                mbL + r * 256 + ((kt * 64 + q * 16) ^ swzr));
            D = __builtin_amdgcn_mfma_f32_16x16x32_bf16(Ak, Bk, D, 0, 0, 0);
        }
        f32x4 ba = *reinterpret_cast<const f32x4*>(bA1 + wid * 16 + q * 4);
        float a0 = fmaxf(D[0] + ba[0], 0.f), a1v = fmaxf(D[1] + ba[1], 0.f);
        float a2v = fmaxf(D[2] + ba[2], 0.f), a3v = fmaxf(D[3] + ba[3], 0.f);
        *reinterpret_cast<float2*>(&aL[r][wid * 16 + q * 4])     = make_float2(a0, a1v);
        *reinterpret_cast<float2*>(&aL[r][wid * 16 + q * 4 + 2]) = make_float2(a2v, a3v);
    }
    __syncthreads();   // a tile complete

    // ---------------- Phase 3c: out = tanh(a @ W_a2^T + b_a2)
    if (tid < 32) {
        const int s = tid & 15, o = tid >> 4;
        const float* wr = wA2 + o * 64;
        float p = 0.f;
        #pragma unroll
        for (int d = 0; d < 64; ++d) p = fmaf(aL[s][d], wr[d], p);
        outg[(size_t)(eb + s) * 2 + o] = tanhf(p + bA2[o]);
    }
}

extern "C" void kernel_launch(void* const* d_in, const int* in_sizes, int n_in,
                              void* d_out, int out_size, void* d_ws, size_t ws_size,
                              hipStream_t stream) {
    const float* s0   = (const float*)d_in[0];
    const float* s1   = (const float*)d_in[1];
    const float* s2   = (const float*)d_in[2];
    const float* wOwn = (const float*)d_in[3];
    const float* bOwn = (const float*)d_in[4];
    const float* wEnv = (const float*)d_in[5];
    const float* bEnv = (const float*)d_in[6];
    const float* wS1  = (const float*)d_in[7];
    const float* bS1  = (const float*)d_in[8];
    const float* wS2  = (const float*)d_in[9];
    const float* bS2  = (const float*)d_in[10];
    const float* wQ   = (const float*)d_in[11];
    const float* wK   = (const float*)d_in[12];
    const float* wV   = (const float*)d_in[13];
    // d_in[14] (W_cq) / d_in[15] (W_ck): dead code in the reference.
    const float* wCv  = (const float*)d_in[16];
    const float* wMo  = (const float*)d_in[17];
    const float* bMo  = (const float*)d_in[18];
    const float* wA1  = (const float*)d_in[19];
    const float* bA1  = (const float*)d_in[20];
    const float* wA2  = (const float*)d_in[21];
    const float* bA2  = (const float*)d_in[22];
    float* ws  = (float*)d_ws;
    float* out = (float*)d_out;

    hipLaunchKernelGGL(actor_wcvv, dim3(16), dim3(256), 0, stream, wCv, wV, ws);
    hipLaunchKernelGGL(actor_setup, dim3(WS_SETUP_END / 256), dim3(256), 0, stream,
                       wOwn, wEnv, wS1, wS2, wQ, wK, wCv, wMo, wA1, ws);
    hipLaunchKernelGGL(actor_mega, dim3(16384 / 16), dim3(256), 0, stream,
                       s0, s1, s2, bOwn, bEnv, bS1, bS2, bMo, bA1, wA2, bA2,
                       ws, out);
}